// Round 23
// baseline (697.325 us; speedup 1.0000x reference)
//
#include <hip/hip_runtime.h>
#include <hip/hip_cooperative_groups.h>

#define BQ 2048
#define MM 65536
#define CC 128
#define QBS 64
#define NQB 32
#define NSPLIT 64
#define KCHUNK (MM/NSPLIT)      // 1024
#define NBUCKET 1024
#define NACT 1056               // sum of 2*(qb+1), qb=0..31

typedef short short8 __attribute__((ext_vector_type(8)));
typedef float f32x4 __attribute__((ext_vector_type(4)));
typedef unsigned int u32x4 __attribute__((ext_vector_type(4)));
typedef unsigned int u32;

__device__ __forceinline__ unsigned short f2bf(float x) {
    unsigned int u = __builtin_bit_cast(unsigned int, x);
    u = (u + 0x7FFFu + ((u >> 16) & 1u)) >> 16;
    return (unsigned short)u;
}
__device__ __forceinline__ float bf2f(unsigned short u) {
    return __builtin_bit_cast(float, (unsigned int)u << 16);
}
__device__ __forceinline__ int bucket_of(float v) {
    return (int)fminf(fmaxf(v * 1024.0f, 0.0f), 1023.0f);
}
__device__ __forceinline__ u32 cvtpk(float lo, float hi) {
    u32 r;
    asm("v_cvt_pk_bf16_f32 %0, %1, %2" : "=v"(r) : "v"(lo), "v"(hi));
    return r;
}

// 4 coalesced 1KB fragment loads, one asm block (volatile: compiler cannot sink/split)
#define GL4(d0, d1, d2, d3, off, base)                                    \
    asm volatile("global_load_dwordx4 %0, %4, %5 offset:0\n\t"            \
                 "global_load_dwordx4 %1, %4, %5 offset:1024\n\t"         \
                 "global_load_dwordx4 %2, %4, %5 offset:2048\n\t"         \
                 "global_load_dwordx4 %3, %4, %5 offset:3072"             \
                 : "=v"(d0), "=v"(d1), "=v"(d2), "=v"(d3)                 \
                 : "v"(off), "s"(base))

// ---------------- cooperative sort pipeline: hist||qrank -> scanA -> scanB -> scatter
// ---------------- -> sortfix -> cq, with grid-wide syncs (replaces 5+ small launches)
__global__ __launch_bounds__(256) void sort_coop_kernel(
    const float* __restrict__ seed, const float* __restrict__ mst,
    int* __restrict__ qperm, int* __restrict__ qrank, float* __restrict__ seed_s,
    unsigned int* __restrict__ histT, unsigned int* __restrict__ btot,
    unsigned int* __restrict__ gbase,
    int* __restrict__ dperm, float* __restrict__ mst_s, int* __restrict__ cq)
{
    cooperative_groups::grid_group grid = cooperative_groups::this_grid();
    __shared__ __align__(16) char pool[4096];
    const int t = threadIdx.x;
    const int blk = blockIdx.x;

    // ---- phase 0: hist (blocks 0..255) || qrank (blocks 256..511) ----
    if (blk < 256) {
        unsigned int* h = (unsigned int*)pool;
        #pragma unroll
        for (int j = t; j < NBUCKET; j += 256) h[j] = 0;
        __syncthreads();
        int bin = bucket_of(mst[blk*256 + t]);
        atomicAdd(&h[bin], 1u);
        __syncthreads();
        #pragma unroll
        for (int j = t; j < NBUCKET; j += 256) histT[(size_t)j*256 + blk] = h[j];
    } else {
        int q = (blk - 256)*8 + (t >> 5);
        int l32 = t & 31;
        float v = seed[q];
        int r = 0;
        for (int seg = 0; seg < 64; ++seg) {
            int j = seg*32 + l32;
            float u = seed[j];
            r += (u < v) || (u == v && j < q);
        }
        #pragma unroll
        for (int m2 = 1; m2 < 32; m2 <<= 1) r += __shfl_xor(r, m2, 32);
        if (l32 == 0) { qperm[r] = q; qrank[q] = r; seed_s[r] = v; }
    }
    __threadfence();
    grid.sync();

    // ---- phase 1: scanA — 2 buckets per block, one per wave (waves 0,1) ----
    {
        int w = t >> 6, t64 = t & 63;
        if (w < 2) {
            int j = blk*2 + w;
            uint4 v = *(uint4*)(histT + (size_t)j*256 + t64*4);
            unsigned int s0 = v.x, s1 = v.y, s2 = v.z, s3 = v.w;
            unsigned int tsum = s0 + s1 + s2 + s3;
            unsigned int inc = tsum;
            #pragma unroll
            for (int off = 1; off < 64; off <<= 1) {
                unsigned int n = __shfl_up(inc, off, 64);
                if (t64 >= off) inc += n;
            }
            unsigned int ex = inc - tsum;
            uint4 o;
            o.x = ex; o.y = ex + s0; o.z = ex + s0 + s1; o.w = ex + s0 + s1 + s2;
            *(uint4*)(histT + (size_t)j*256 + t64*4) = o;
            if (t64 == 63) btot[j] = inc;
        }
    }
    __threadfence();
    grid.sync();

    // ---- phase 2: scanB — exclusive scan of 1024 bucket totals (block 0) ----
    if (blk == 0) {
        unsigned int* sc = (unsigned int*)pool;
        unsigned int b0 = btot[t*4], b1 = btot[t*4+1], b2 = btot[t*4+2], b3 = btot[t*4+3];
        unsigned int tsum = b0 + b1 + b2 + b3;
        sc[t] = tsum;
        __syncthreads();
        for (int off = 1; off < 256; off <<= 1) {
            unsigned int y = (t >= off) ? sc[t - off] : 0u;
            __syncthreads();
            sc[t] += y;
            __syncthreads();
        }
        unsigned int ex = sc[t] - tsum;
        gbase[t*4]   = ex;
        gbase[t*4+1] = ex + b0;
        gbase[t*4+2] = ex + b0 + b1;
        gbase[t*4+3] = ex + b0 + b1 + b2;
    }
    __threadfence();
    grid.sync();

    // ---- phase 3: scatter (blocks 0..255) ----
    if (blk < 256) {
        int* bins = (int*)pool;
        int i = blk*256 + t;
        float v = mst[i];
        int bin = bucket_of(v);
        bins[t] = bin;
        __syncthreads();
        int pos = 0;
        for (int j = 0; j < t; ++j) pos += (bins[j] == bin);
        unsigned int dest = gbase[bin] + histT[(size_t)bin*256 + blk] + pos;
        dperm[dest] = i;
        mst_s[dest] = v;
    }
    __threadfence();
    grid.sync();

    // ---- phase 4: sortfix — 2 buckets sequentially per block (256 thr each) ----
    {
        float* vals = (float*)pool;            // [512]
        int* idxs   = (int*)(pool + 2048);     // [512]
        for (int sub = 0; sub < 2; ++sub) {
            int bb = blk*2 + sub;
            int base = (int)gbase[bb];
            int n = (int)btot[bb];
            if (n > 512) n = 512;
            __syncthreads();
            if (n > 1)
                for (int i = t; i < n; i += 256) { vals[i] = mst_s[base+i]; idxs[i] = dperm[base+i]; }
            __syncthreads();
            if (n > 1)
                for (int i = t; i < n; i += 256) {
                    float v = vals[i]; int d = idxs[i];
                    int rank = 0;
                    for (int j = 0; j < n; ++j) {
                        float vj = vals[j];
                        rank += (vj < v) || (vj == v && idxs[j] < d);
                    }
                    mst_s[base + rank] = v;
                    dperm[base + rank] = d;
                }
        }
    }
    __threadfence();
    grid.sync();

    // ---- phase 5: cq — exact cut per sorted query (blocks 0..127, 16 lanes/query) ----
    if (blk < 128) {
        int qi = blk*16 + (t >> 4);
        int l16 = t & 15;
        float s = seed_s[qi];
        int b = bucket_of(s);
        int base = (int)gbase[b];
        int n = (int)btot[b];
        int cnt = 0;
        for (int i = l16; i < n; i += 16) cnt += (mst_s[base + i] <= s) ? 1 : 0;
        #pragma unroll
        for (int m2 = 1; m2 < 16; m2 <<= 1) cnt += __shfl_xor(cnt, m2, 64);
        if (l16 == 0) cq[qi] = base + cnt;
    }
}

// ---------------- K_B: mem_norm (0..511) || query_prep (512..1023) || etab (1024) -----
__global__ __launch_bounds__(256) void kb_kernel(
    const float* __restrict__ mx, const int* __restrict__ dperm,
    const int* __restrict__ memy,
    char* __restrict__ FK, char* __restrict__ FV, float* __restrict__ y_s,
    const float* __restrict__ feat, const float* __restrict__ keyw,
    const float* __restrict__ keyb, const float* __restrict__ msgw,
    const float* __restrict__ msgb, const float* __restrict__ yemb,
    const int* __restrict__ qrank,
    unsigned short* __restrict__ q2, float* __restrict__ a, float* __restrict__ etab)
{
    __shared__ __align__(16) char smpool[35328];
    const int t = threadIdx.x;
    const int blk = blockIdx.x;

    if (blk < 512) {
        // ----- mem_norm: l2norm gather -> FK/FV fragment-major + y_s -----
        unsigned short* tile = (unsigned short*)smpool;            // [128][132]
        float* rs   = (float*)(smpool + 33792);
        float* invn = (float*)(smpool + 34304);
        int* operm  = (int*)(smpool + 34816);
        const int kb0 = blk * 128;
        const int gt0 = blk * 2;

        if (t < 128) operm[t] = dperm[kb0 + t];
        __syncthreads();
        if (t < 128) y_s[kb0 + t] = (float)memy[operm[t]];

        float4 vals[16];
        #pragma unroll
        for (int i = 0; i < 16; ++i) {
            int f4 = t + 256*i;
            int row = f4 >> 5, col4 = f4 & 31;
            float4 v = *(const float4*)(mx + (size_t)operm[row]*CC + col4*4);
            vals[i] = v;
            float s = v.x*v.x + v.y*v.y + v.z*v.z + v.w*v.w;
            #pragma unroll
            for (int m2 = 1; m2 < 32; m2 <<= 1) s += __shfl_xor(s, m2, 64);
            if ((t & 31) == 0) rs[row] = s;
        }
        __syncthreads();
        if (t < 128) invn[t] = 1.0f / fmaxf(sqrtf(rs[t]), 1e-12f);
        __syncthreads();
        #pragma unroll
        for (int i = 0; i < 16; ++i) {
            int f4 = t + 256*i;
            int row = f4 >> 5, col4 = f4 & 31;
            float sc = invn[row];
            float4 v = vals[i];
            ushort4 o;
            o.x = f2bf(v.x*sc); o.y = f2bf(v.y*sc); o.z = f2bf(v.z*sc); o.w = f2bf(v.w*sc);
            *(ushort4*)&tile[row*132 + col4*4] = o;
        }
        __syncthreads();
        #pragma unroll
        for (int i = 0; i < 8; ++i) {
            int u = t + 256*i;
            int tl = u >> 10;
            int s  = (u >> 8) & 3;
            int cs = (u >> 6) & 3;
            int ln = u & 63;
            int aa = ln & 15, grp = ln >> 4;
            int row = tl*64 + ((s >> 1) << 5) + ((aa & 12) << 1) + ((s & 1) << 2) + (aa & 3);
            int col = cs*32 + grp*8;
            ushort4 p0 = *(ushort4*)&tile[row*132 + col];
            ushort4 p1 = *(ushort4*)&tile[row*132 + col + 4];
            char* dst = FK + ((size_t)(gt0 + tl)*16 + s*4 + cs)*1024 + ln*16;
            *(ushort4*)dst = p0;
            *(ushort4*)(dst + 8) = p1;
        }
        #pragma unroll
        for (int i = 0; i < 8; ++i) {
            int u = t + 256*i;
            int tl = u >> 10;
            int v2 = u & 1023;
            int sc = v2 >> 7;
            int rest = v2 & 127;
            int kk = rest >> 6;
            int ln = rest & 63;
            int c = sc*16 + (ln & 15);
            int key0 = tl*64 + kk*32 + (ln >> 4)*8;
            u32 w0 = (u32)tile[(key0+0)*132 + c] | ((u32)tile[(key0+1)*132 + c] << 16);
            u32 w1 = (u32)tile[(key0+2)*132 + c] | ((u32)tile[(key0+3)*132 + c] << 16);
            u32 w2 = (u32)tile[(key0+4)*132 + c] | ((u32)tile[(key0+5)*132 + c] << 16);
            u32 w3 = (u32)tile[(key0+6)*132 + c] | ((u32)tile[(key0+7)*132 + c] << 16);
            uint4 o; o.x = w0; o.y = w1; o.z = w2; o.w = w3;
            *(uint4*)(FV + ((size_t)(gt0 + tl)*16 + sc*2 + kk)*1024 + ln*16) = o;
        }
    } else if (blk <= 1024) {
        // ----- query_prep (+ etab on blk==1024) -----
        if (blk == 1024) {
            if (t < 128) {
                float acc0 = msgb[t], acc1 = msgb[t];
                for (int c2 = 0; c2 < 128; ++c2) {
                    float w3 = msgw[(256 + c2)*128 + t];
                    acc0 = fmaf(yemb[c2], w3, acc0);
                    acc1 = fmaf(yemb[128 + c2], w3, acc1);
                }
                etab[t] = acc0;
                etab[128 + t] = acc1;
            }
            return;
        }
        float* fl = (float*)smpool;                 // [4][128]
        float* t1 = (float*)(smpool + 2048);        // [4][128]
        const int w = t >> 6;
        const int lane = t & 63;
        const int b = (blk - 512)*4 + w;
        const int j0 = lane, j1 = lane + 64;
        float f0 = feat[b*CC + j0], f1 = feat[b*CC + j1];
        fl[w*128 + j0] = f0; fl[w*128 + j1] = f1;
        float s = f0*f0 + f1*f1;
        #pragma unroll
        for (int m2 = 1; m2 < 64; m2 <<= 1) s += __shfl_xor(s, m2, 64);
        float invn = 1.0f / fmaxf(sqrtf(s), 1e-12f);
        __syncthreads();
        float g0 = 0.f, g1 = 0.f, a0 = 0.f, a1 = 0.f;
        for (int i = 0; i < 128; ++i) {
            float x = fl[w*128 + i];
            g0 = fmaf(x, keyw[i*128 + j0], g0);
            g1 = fmaf(x, keyw[i*128 + j1], g1);
            a0 = fmaf(x, msgw[i*128 + j0], a0);
            a1 = fmaf(x, msgw[i*128 + j1], a1);
        }
        t1[w*128 + j0] = g0*invn + keyb[j0];
        t1[w*128 + j1] = g1*invn + keyb[j1];
        a[b*CC + j0] = a0;
        a[b*CC + j1] = a1;
        __syncthreads();
        float q0 = 0.f, q1 = 0.f;
        for (int c2 = 0; c2 < 128; ++c2) {
            float u = t1[w*128 + c2];
            q0 = fmaf(u, keyw[j0*128 + c2], q0);
            q1 = fmaf(u, keyw[j1*128 + c2], q1);
        }
        const float LOG2E = 1.4426950408889634f;
        int rb = qrank[b];
        q2[rb*CC + j0] = f2bf(q0 * LOG2E);
        q2[rb*CC + j1] = f2bf(q1 * LOG2E);
    }
}

// ---------------- flash attention: r18 verbatim (best measured: 104us) ----------------
// asm-batched loads (16 K + 4 y, then 16 V) with counted vmcnt; (256,2) = no spills.
__global__ __launch_bounds__(256, 2) void attn_kernel(
    const char* __restrict__ FK,
    const char* __restrict__ FV,
    const unsigned short* __restrict__ q2,
    const int* __restrict__ cq,
    const float* __restrict__ y_s,
    unsigned short* __restrict__ Upart,
    float* __restrict__ lpart,
    float* __restrict__ wypart)
{
    __shared__ __align__(16) char bounce[4][4352];   // per-wave transpose bounce

    const int tid = threadIdx.x;
    const int w = tid >> 6;
    const int lane = tid & 63;
    const int g = lane >> 4;
    const int l15 = lane & 15;

    // staircase id -> (qb, chunk): expected-active cells (chunk < 2*(qb+1)) first
    int qb, chunk;
    {
        int id = blockIdx.x;                 // 0..2047 over 32 x 64 cells
        if (id < NACT) {
            int q = 0, base = 0;
            while (id >= base + 2*(q + 1)) { base += 2*(q + 1); ++q; }
            qb = q; chunk = id - base;
        } else {
            int k = id - NACT;
            int q = 0;
            while (k >= 64 - 2*(q + 1)) { k -= 64 - 2*(q + 1); ++q; }
            qb = q; chunk = 2*(q + 1) + k;
        }
    }

    const int cbase = chunk*KCHUNK;
    const int cqmax = cq[qb*QBS + QBS - 1];
    int ntiles = (cqmax - cbase + 63) >> 6;
    if (ntiles <= 0) return;                 // matches final's na predicate exactly
    if (ntiles > KCHUNK/64) ntiles = KCHUNK/64;

    const int qrow0 = qb*QBS + w*16;
    short8 qf[4];
    #pragma unroll
    for (int cs = 0; cs < 4; ++cs)
        qf[cs] = *(const short8*)(q2 + (size_t)(qrow0 + l15)*CC + cs*32 + g*8);
    const int cqv = cq[qrow0 + l15];
    const int g8 = g*8;

    f32x4 accU[8];
    #pragma unroll
    for (int n = 0; n < 8; ++n) accU[n] = (f32x4)0.f;
    float accl = 0.f, accw = 0.f;

    const int voff = lane * 16;      // byte offset within a 1KB fragment
    const int vyoff = g * 32;        // byte offset into y row (g8 floats)

    const int gt00 = cbase >> 6;
    for (int kt2 = 0; kt2 < ntiles; ++kt2) {
        const int kb0 = cbase + kt2*64;
        const char* Kf = FK + (size_t)(gt00 + kt2)*16384;
        const char* Vf = FV + (size_t)(gt00 + kt2)*16384;
        const float* yb = y_s + kb0;
        const int cut = cqv - kb0;

        // ---- issue all 16 K fragment loads + 4 y loads (20 in flight) ----
        short8 kf00, kf01, kf02, kf03, kf10, kf11, kf12, kf13;
        short8 kf20, kf21, kf22, kf23, kf30, kf31, kf32, kf33;
        float4 y0, y1, y2, y3;
        GL4(kf00, kf01, kf02, kf03, voff, Kf);
        GL4(kf10, kf11, kf12, kf13, voff, Kf + 4096);
        GL4(kf20, kf21, kf22, kf23, voff, Kf + 8192);
        GL4(kf30, kf31, kf32, kf33, voff, Kf + 12288);
        asm volatile("global_load_dwordx4 %0, %4, %5 offset:0\n\t"
                     "global_load_dwordx4 %1, %4, %5 offset:16\n\t"
                     "global_load_dwordx4 %2, %4, %5 offset:128\n\t"
                     "global_load_dwordx4 %3, %4, %5 offset:144"
                     : "=v"(y0), "=v"(y1), "=v"(y2), "=v"(y3)
                     : "v"(vyoff), "s"(yb));

        asm volatile("s_waitcnt vmcnt(4)" ::: "memory");   // K ready; y in flight
        __builtin_amdgcn_sched_barrier(0);

        // ---- QK: 16 MFMA ----
        f32x4 st0 = (f32x4)0.f, st1 = (f32x4)0.f, st2 = (f32x4)0.f, st3 = (f32x4)0.f;
        st0 = __builtin_amdgcn_mfma_f32_16x16x32_bf16(kf00, qf[0], st0, 0, 0, 0);
        st0 = __builtin_amdgcn_mfma_f32_16x16x32_bf16(kf01, qf[1], st0, 0, 0, 0);
        st0 = __builtin_amdgcn_mfma_f32_16x16x32_bf16(kf02, qf[2], st0, 0, 0, 0);
        st0 = __builtin_amdgcn_mfma_f32_16x16x32_bf16(kf03, qf[3], st0, 0, 0, 0);
        st1 = __builtin_amdgcn_mfma_f32_16x16x32_bf16(kf10, qf[0], st1, 0, 0, 0);
        st1 = __builtin_amdgcn_mfma_f32_16x16x32_bf16(kf11, qf[1], st1, 0, 0, 0);
        st1 = __builtin_amdgcn_mfma_f32_16x16x32_bf16(kf12, qf[2], st1, 0, 0, 0);
        st1 = __builtin_amdgcn_mfma_f32_16x16x32_bf16(kf13, qf[3], st1, 0, 0, 0);
        st2 = __builtin_amdgcn_mfma_f32_16x16x32_bf16(kf20, qf[0], st2, 0, 0, 0);
        st2 = __builtin_amdgcn_mfma_f32_16x16x32_bf16(kf21, qf[1], st2, 0, 0, 0);
        st2 = __builtin_amdgcn_mfma_f32_16x16x32_bf16(kf22, qf[2], st2, 0, 0, 0);
        st2 = __builtin_amdgcn_mfma_f32_16x16x32_bf16(kf23, qf[3], st2, 0, 0, 0);
        st3 = __builtin_amdgcn_mfma_f32_16x16x32_bf16(kf30, qf[0], st3, 0, 0, 0);
        st3 = __builtin_amdgcn_mfma_f32_16x16x32_bf16(kf31, qf[1], st3, 0, 0, 0);
        st3 = __builtin_amdgcn_mfma_f32_16x16x32_bf16(kf32, qf[2], st3, 0, 0, 0);
        st3 = __builtin_amdgcn_mfma_f32_16x16x32_bf16(kf33, qf[3], st3, 0, 0, 0);

        // ---- issue all 16 V fragment loads (K regs now dead) ----
        short8 vfa0, vfb0, vfa1, vfb1, vfa2, vfb2, vfa3, vfb3;
        short8 vfa4, vfb4, vfa5, vfb5, vfa6, vfb6, vfa7, vfb7;
        GL4(vfa0, vfb0, vfa1, vfb1, voff, Vf);
        GL4(vfa2, vfb2, vfa3, vfb3, voff, Vf + 4096);
        GL4(vfa4, vfb4, vfa5, vfb5, voff, Vf + 8192);
        GL4(vfa6, vfb6, vfa7, vfb7, voff, Vf + 12288);

        asm volatile("s_waitcnt vmcnt(16)" ::: "memory");  // y ready; V in flight
        __builtin_amdgcn_sched_barrier(0);

        // ---- P = exp2(S) masked; stats; pack bf16 in-lane (covers V latency) ----
        u32 pw[8];
        {
            const int kb_ = g8;
            float p0 = (kb_ + 0 < cut) ? exp2f(st0[0]) : 0.f;
            float p1 = (kb_ + 1 < cut) ? exp2f(st0[1]) : 0.f;
            float p2 = (kb_ + 2 < cut) ? exp2f(st0[2]) : 0.f;
            float p3 = (kb_ + 3 < cut) ? exp2f(st0[3]) : 0.f;
            accl += p0 + p1 + p2 + p3;
            accw = fmaf(p0, y0.x, fmaf(p1, y0.y, fmaf(p2, y0.z, fmaf(p3, y0.w, accw))));
            pw[0] = cvtpk(p0, p1); pw[1] = cvtpk(p2, p3);
        }
        {
            const int kb_ = g8 + 4;
            float p0 = (kb_ + 0 < cut) ? exp2f(st1[0]) : 0.f;
            float p1 = (kb_ + 1 < cut) ? exp2f(st1[1]) : 0.f;
            float p2 = (kb_ + 2 < cut) ? exp2f(st1[2]) : 0.f;
            float p3 = (kb_ + 3 < cut) ? exp2f(st1[3]) : 0.f;
            accl += p0 + p1 + p2 + p3;
            accw = fmaf(p0, y1.x, fmaf(p1, y1.y, fmaf(p2, y1.z, fmaf(p3, y1.w, accw))));
            pw[2] = cvtpk(p0, p1); pw[3] = cvtpk(p2, p3);
        }
        {
            const int kb_ = 32 + g8;
            float p0 = (kb_ + 0 < cut) ? exp2f(st2[0]) : 0.f;
            float p1 = (kb_ + 1 < cut) ? exp2f(st2[1]) : 0.f;
            float p2 = (kb_ + 2 < cut) ? exp2f(st2[2]) : 0.f;
            float p3 = (kb_ + 3 < cut) ? exp2f(st2[3]) : 0.f;
            accl += p0 + p1 + p2 + p3;
            accw = fmaf(p0, y2.x, fmaf(p1, y2.y, fmaf(p2, y2.z, fmaf(p3, y2.w, accw))));
            pw[4] = cvtpk(p0, p1); pw[5] = cvtpk(p2, p3);
        }
        {
            const int kb_ = 32 + g8 + 4;
            float p0 = (kb_ + 0 < cut) ? exp2f(st3[0]) : 0.f;
            float p1 = (kb_ + 1 < cut) ? exp2f(st3[1]) : 0.f;
            float p2 = (kb_ + 2 < cut) ? exp2f(st3[2]) : 0.f;
            float p3 = (kb_ + 3 < cut) ? exp2f(st3[3]) : 0.f;
            accl += p0 + p1 + p2 + p3;
            accw = fmaf(p0, y3.x, fmaf(p1, y3.y, fmaf(p2, y3.z, fmaf(p3, y3.w, accw))));
            pw[6] = cvtpk(p0, p1); pw[7] = cvtpk(p2, p3);
        }
        u32x4 t0v = {pw[0], pw[1], pw[2], pw[3]};
        u32x4 t1v = {pw[4], pw[5], pw[6], pw[7]};
        short8 pa0 = __builtin_bit_cast(short8, t0v);
        short8 pa1 = __builtin_bit_cast(short8, t1v);

        asm volatile("s_waitcnt vmcnt(0)" ::: "memory");   // V ready
        __builtin_amdgcn_sched_barrier(0);

        // ---- PV: 16 MFMA ----
        accU[0] = __builtin_amdgcn_mfma_f32_16x16x32_bf16(vfa0, pa0, accU[0], 0, 0, 0);
        accU[0] = __builtin_amdgcn_mfma_f32_16x16x32_bf16(vfb0, pa1, accU[0], 0, 0, 0);
        accU[1] = __builtin_amdgcn_mfma_f32_16x16x32_bf16(vfa1, pa0, accU[1], 0, 0, 0);
        accU[1] = __builtin_amdgcn_mfma_f32_16x16x32_bf16(vfb1, pa1, accU[1], 0, 0, 0);
        accU[2] = __builtin_amdgcn_mfma_f32_16x16x32_bf16(vfa2, pa0, accU[2], 0, 0, 0);
        accU[2] = __builtin_amdgcn_mfma_f32_16x16x32_bf16(vfb2, pa1, accU[2], 0, 0, 0);
        accU[3] = __builtin_amdgcn_mfma_f32_16x16x32_bf16(vfa3, pa0, accU[3], 0, 0, 0);
        accU[3] = __builtin_amdgcn_mfma_f32_16x16x32_bf16(vfb3, pa1, accU[3], 0, 0, 0);
        accU[4] = __builtin_amdgcn_mfma_f32_16x16x32_bf16(vfa4, pa0, accU[4], 0, 0, 0);
        accU[4] = __builtin_amdgcn_mfma_f32_16x16x32_bf16(vfb4, pa1, accU[4], 0, 0, 0);
        accU[5] = __builtin_amdgcn_mfma_f32_16x16x32_bf16(vfa5, pa0, accU[5], 0, 0, 0);
        accU[5] = __builtin_amdgcn_mfma_f32_16x16x32_bf16(vfb5, pa1, accU[5], 0, 0, 0);
        accU[6] = __builtin_amdgcn_mfma_f32_16x16x32_bf16(vfa6, pa0, accU[6], 0, 0, 0);
        accU[6] = __builtin_amdgcn_mfma_f32_16x16x32_bf16(vfb6, pa1, accU[6], 0, 0, 0);
        accU[7] = __builtin_amdgcn_mfma_f32_16x16x32_bf16(vfa7, pa0, accU[7], 0, 0, 0);
        accU[7] = __builtin_amdgcn_mfma_f32_16x16x32_bf16(vfb7, pa1, accU[7], 0, 0, 0);
    }

    // ---- epilogue (per-wave, no block barriers; r12-verified) ----
    const int cell = qb*NSPLIT + chunk;
    accl += __shfl_xor(accl, 16, 64); accl += __shfl_xor(accl, 32, 64);
    accw += __shfl_xor(accw, 16, 64); accw += __shfl_xor(accw, 32, 64);
    if (lane < 16) {
        lpart [cell*QBS + w*16 + lane] = accl;
        wypart[cell*QBS + w*16 + lane] = accw;
    }
    char* bw = bounce[w];
    #pragma unroll
    for (int sc = 0; sc < 8; ++sc) {
        #pragma unroll
        for (int jp = 0; jp < 2; ++jp) {
            u32 pk = cvtpk(accU[sc][2*jp], accU[sc][2*jp + 1]);
            *(u32*)(bw + l15*272 + (sc*16 + g*4 + 2*jp)*2) = pk;
        }
    }
    asm volatile("s_waitcnt lgkmcnt(0)" ::: "memory");
    __builtin_amdgcn_sched_barrier(0);
    #pragma unroll
    for (int p = 0; p < 4; ++p) {
        int seg = p*4 + (lane & 3);
        int q = lane >> 2;
        uint4 v = *(const uint4*)(bw + q*272 + seg*16);
        *(uint4*)((char*)Upart + (size_t)(cell*QBS + w*16 + q)*256 + seg*16) = v;
    }
}

// ---------------- fused combine + epilogue MLP (r18, verified) ------------------------
__global__ __launch_bounds__(256) void final_kernel(
    const float* __restrict__ feat, const unsigned short* __restrict__ Upart,
    const float* __restrict__ lpart, const float* __restrict__ wypart,
    const int* __restrict__ cq,
    const float* __restrict__ a, const float* __restrict__ etab,
    const float* __restrict__ msgw, const int* __restrict__ qperm,
    const float* __restrict__ uw1, const float* __restrict__ ub1,
    const float* __restrict__ uw2, const float* __restrict__ ub2,
    float* __restrict__ out)
{
    __shared__ float fl[4][128], t0[4][128], t1l[4][128];
    const int t = threadIdx.x;
    const int w = t >> 6;
    const int lane = t & 63;
    const int b = blockIdx.x*4 + w;      // sorted row
    const int qb = b >> 6;
    const int cqmax = cq[qb*QBS + QBS - 1];
    int na = (cqmax + KCHUNK - 1) >> 10; // KCHUNK = 1024
    if (na > NSPLIT) na = NSPLIT;        // >= 1 since key 0 always allowed
    const int ob = qperm[b];             // original row
    const int rowin = b & (QBS - 1);
    const int j0 = lane, j1 = lane + 64;
    float f0 = feat[ob*CC + j0], f1 = feat[ob*CC + j1];
    fl[w][j0] = f0; fl[w][j1] = f1;
    float lv = 0.f, wv = 0.f;
    if (lane < na) {
        int o = (qb*NSPLIT + lane)*QBS + rowin;
        lv = lpart[o]; wv = wypart[o];
    }
    #pragma unroll
    for (int m2 = 1; m2 < 64; m2 <<= 1) {
        lv += __shfl_xor(lv, m2, 64);
        wv += __shfl_xor(wv, m2, 64);
    }
    float ua = 0.f, ub = 0.f;
    for (int j = 0; j < na; ++j) {
        const unsigned short* up = Upart + (size_t)((qb*NSPLIT + j)*QBS + rowin)*CC;
        u32 pk = *(const u32*)(up + 2*lane);
        ua += bf2f((unsigned short)(pk & 0xffff));
        ub += bf2f((unsigned short)(pk >> 16));
    }
    t0[w][2*lane] = ua; t0[w][2*lane + 1] = ub;
    __syncthreads();
    float linv = 1.0f / lv;
    float s1 = wv / lv;
    float acc0 = 0.f, acc1 = 0.f;
    for (int i = 0; i < 128; ++i) {
        float x = t0[w][i];
        acc0 = fmaf(x, msgw[(128 + i)*128 + j0], acc0);
        acc1 = fmaf(x, msgw[(128 + i)*128 + j1], acc1);
    }
    float mix0 = (1.f - s1)*etab[j0] + s1*etab[128 + j0];
    float mix1 = (1.f - s1)*etab[j1] + s1*etab[128 + j1];
    float hg0 = a[ob*CC + j0] + acc0*linv + mix0;
    float hg1 = a[ob*CC + j1] + acc1*linv + mix1;
    __syncthreads();
    t0[w][j0] = hg0; t0[w][j1] = hg1;
    __syncthreads();
    float h0 = ub1[j0], h1 = ub1[j1];
    for (int i = 0; i < 128; ++i) {
        float xf = fl[w][i];
        float xh = t0[w][i];
        h0 = fmaf(xf, uw1[i*128 + j0], h0);
        h1 = fmaf(xf, uw1[i*128 + j1], h1);
        h0 = fmaf(xh, uw1[(128 + i)*128 + j0], h0);
        h1 = fmaf(xh, uw1[(128 + i)*128 + j1], h1);
    }
    h0 = fmaxf(h0, 0.f); h1 = fmaxf(h1, 0.f);
    t1l[w][j0] = h0; t1l[w][j1] = h1;
    __syncthreads();
    float o0 = ub2[j0], o1 = ub2[j1];
    for (int i = 0; i < 128; ++i) {
        float x = t1l[w][i];
        o0 = fmaf(x, uw2[i*128 + j0], o0);
        o1 = fmaf(x, uw2[i*128 + j1], o1);
    }
    out[ob*CC + j0] = f0 + o0;
    out[ob*CC + j1] = f1 + o1;
}

extern "C" void kernel_launch(void* const* d_in, const int* in_sizes, int n_in,
                              void* d_out, int out_size, void* d_ws, size_t ws_size,
                              hipStream_t stream) {
    (void)in_sizes; (void)n_in; (void)out_size; (void)ws_size;
    const float* feature  = (const float*)d_in[0];
    const float* memory_x = (const float*)d_in[1];
    const int*   memory_y = (const int*)d_in[2];
    const float* seed_t   = (const float*)d_in[3];
    const float* mem_st   = (const float*)d_in[4];
    const float* key_w    = (const float*)d_in[5];
    const float* key_b    = (const float*)d_in[6];
    const float* msg_w    = (const float*)d_in[7];
    const float* msg_b    = (const float*)d_in[8];
    const float* upd_w1   = (const float*)d_in[9];
    const float* upd_b1   = (const float*)d_in[10];
    const float* upd_w2   = (const float*)d_in[11];
    const float* upd_b2   = (const float*)d_in[12];
    const float* y_emb    = (const float*)d_in[13];
    float* out = (float*)d_out;

    // ---- bump-allocated workspace (256B aligned) ----
    char* ws = (char*)d_ws;
    size_t off = 0;
    auto A = [&](size_t bytes) -> char* {
        char* p = ws + off;
        off += (bytes + 255) & ~(size_t)255;
        return p;
    };
    char* FK = A((size_t)(MM/64)*16*1024);                               // 16.78 MB
    char* FV = A((size_t)(MM/64)*16*1024);                               // 16.78 MB
    unsigned short* q2    = (unsigned short*)A((size_t)BQ*CC*2);         // 512 KB
    float* a      = (float*)A((size_t)BQ*CC*4);                          // 1 MB
    float* etab   = (float*)A(2*CC*4);
    float* lpart  = (float*)A((size_t)NQB*NSPLIT*QBS*4);                 // 512 KB
    float* wypart = (float*)A((size_t)NQB*NSPLIT*QBS*4);                 // 512 KB
    int*   dperm  = (int*)A((size_t)MM*4);                               // 256 KB
    float* mst_s  = (float*)A((size_t)MM*4);                             // 256 KB
    float* y_s    = (float*)A((size_t)MM*4);                             // 256 KB
    unsigned int* btot  = (unsigned int*)A(NBUCKET*4);
    unsigned int* gbase = (unsigned int*)A(NBUCKET*4);
    int*   qperm  = (int*)A(BQ*4);
    int*   qrank  = (int*)A(BQ*4);
    float* seed_s = (float*)A(BQ*4);
    int*   cqbuf  = (int*)A(BQ*4);
    unsigned int* histT = (unsigned int*)A((size_t)NBUCKET*256*4);       // 1 MB
    unsigned short* Upart = (unsigned short*)A((size_t)NQB*NSPLIT*QBS*CC*2); // 33.5 MB

    void* cargs[] = {
        (void*)&seed_t, (void*)&mem_st, (void*)&qperm, (void*)&qrank, (void*)&seed_s,
        (void*)&histT, (void*)&btot, (void*)&gbase,
        (void*)&dperm, (void*)&mst_s, (void*)&cqbuf
    };
    hipLaunchCooperativeKernel((void*)sort_coop_kernel, dim3(512), dim3(256),
                               cargs, 0, stream);
    kb_kernel<<<1025, 256, 0, stream>>>(memory_x, dperm, memory_y, FK, FV, y_s,
                                        feature, key_w, key_b, msg_w, msg_b, y_emb,
                                        qrank, q2, a, etab);
    attn_kernel<<<NQB*NSPLIT, 256, 0, stream>>>(FK, FV, q2, cqbuf, y_s,
                                                Upart, lpart, wypart);
    final_kernel<<<BQ/4, 256, 0, stream>>>(feature, Upart, lpart, wypart, cqbuf,
                                           a, etab, msg_w, qperm,
                                           upd_w1, upd_b1, upd_w2, upd_b2, out);
}

// Round 24
// 246.397 us; speedup vs baseline: 2.8301x; 2.8301x over previous
//
#include <hip/hip_runtime.h>

#define BQ 2048
#define MM 65536
#define CC 128
#define QBS 64
#define NQB 32
#define NSPLIT 64
#define KCHUNK (MM/NSPLIT)      // 1024
#define NBUCKET 1024
#define NACT 1056               // active cells: sum over chunks of (32 - chunk/2)

typedef short short8 __attribute__((ext_vector_type(8)));
typedef float f32x4 __attribute__((ext_vector_type(4)));
typedef unsigned int u32x4 __attribute__((ext_vector_type(4)));
typedef unsigned int u32;

__device__ __forceinline__ unsigned short f2bf(float x) {
    unsigned int u = __builtin_bit_cast(unsigned int, x);
    u = (u + 0x7FFFu + ((u >> 16) & 1u)) >> 16;
    return (unsigned short)u;
}
__device__ __forceinline__ float bf2f(unsigned short u) {
    return __builtin_bit_cast(float, (unsigned int)u << 16);
}
__device__ __forceinline__ int bucket_of(float v) {
    return (int)fminf(fmaxf(v * 1024.0f, 0.0f), 1023.0f);
}
__device__ __forceinline__ u32 cvtpk(float lo, float hi) {
    u32 r;
    asm("v_cvt_pk_bf16_f32 %0, %1, %2" : "=v"(r) : "v"(lo), "v"(hi));
    return r;
}

// 4 coalesced 1KB fragment loads, one asm block (volatile: compiler cannot sink/split)
#define GL4(d0, d1, d2, d3, off, base)                                    \
    asm volatile("global_load_dwordx4 %0, %4, %5 offset:0\n\t"            \
                 "global_load_dwordx4 %1, %4, %5 offset:1024\n\t"         \
                 "global_load_dwordx4 %2, %4, %5 offset:2048\n\t"         \
                 "global_load_dwordx4 %3, %4, %5 offset:3072"             \
                 : "=v"(d0), "=v"(d1), "=v"(d2), "=v"(d3)                 \
                 : "v"(off), "s"(base))

// ---------------- K_A: qrank (blocks 0..255)  ||  hist (blocks 256..511) -------------
__global__ __launch_bounds__(256) void ka_kernel(
    const float* __restrict__ seed, const float* __restrict__ mst,
    int* __restrict__ qperm, int* __restrict__ qrank, float* __restrict__ seed_s,
    unsigned int* __restrict__ histT)
{
    __shared__ unsigned int h[NBUCKET];
    int t = threadIdx.x;
    if (blockIdx.x < 256) {
        int q = blockIdx.x*8 + (t >> 5);
        int l32 = t & 31;
        float v = seed[q];
        int r = 0;
        for (int seg = 0; seg < 64; ++seg) {
            int j = seg*32 + l32;
            float u = seed[j];
            r += (u < v) || (u == v && j < q);
        }
        #pragma unroll
        for (int m2 = 1; m2 < 32; m2 <<= 1) r += __shfl_xor(r, m2, 32);
        if (l32 == 0) { qperm[r] = q; qrank[q] = r; seed_s[r] = v; }
    } else {
        int b = blockIdx.x - 256;
        #pragma unroll
        for (int j = t; j < NBUCKET; j += 256) h[j] = 0;
        __syncthreads();
        int bin = bucket_of(mst[b*256 + t]);
        atomicAdd(&h[bin], 1u);
        __syncthreads();
        #pragma unroll
        for (int j = t; j < NBUCKET; j += 256) histT[(size_t)j*256 + b] = h[j];
    }
}

__global__ __launch_bounds__(64) void sort_scanA_kernel(
    unsigned int* __restrict__ histT, unsigned int* __restrict__ btot)
{
    int j = blockIdx.x;
    int t = threadIdx.x;
    uint4 v = *(uint4*)(histT + (size_t)j*256 + t*4);
    unsigned int s0 = v.x, s1 = v.y, s2 = v.z, s3 = v.w;
    unsigned int tsum = s0 + s1 + s2 + s3;
    unsigned int inc = tsum;
    #pragma unroll
    for (int off = 1; off < 64; off <<= 1) {
        unsigned int n = __shfl_up(inc, off, 64);
        if (t >= off) inc += n;
    }
    unsigned int ex = inc - tsum;
    uint4 o;
    o.x = ex; o.y = ex + s0; o.z = ex + s0 + s1; o.w = ex + s0 + s1 + s2;
    *(uint4*)(histT + (size_t)j*256 + t*4) = o;
    if (t == 63) btot[j] = inc;
}

__global__ __launch_bounds__(1024) void sort_scanB_kernel(
    const unsigned int* __restrict__ btot, unsigned int* __restrict__ gbase)
{
    __shared__ unsigned int sc[NBUCKET];
    int j = threadIdx.x;
    unsigned int tot = btot[j];
    sc[j] = tot;
    __syncthreads();
    for (int off = 1; off < NBUCKET; off <<= 1) {
        unsigned int y = (j >= off) ? sc[j - off] : 0u;
        __syncthreads();
        sc[j] += y;
        __syncthreads();
    }
    gbase[j] = sc[j] - tot;
}

__global__ __launch_bounds__(256) void sort_scatter_kernel(
    const float* __restrict__ mst, const unsigned int* __restrict__ histT,
    const unsigned int* __restrict__ gbase,
    int* __restrict__ dperm, float* __restrict__ mst_s)
{
    __shared__ int bins[256];
    int t = threadIdx.x, b = blockIdx.x;
    int i = b*256 + t;
    float v = mst[i];
    int bin = bucket_of(v);
    bins[t] = bin;
    __syncthreads();
    int pos = 0;
    for (int j = 0; j < t; ++j) pos += (bins[j] == bin);
    unsigned int dest = gbase[bin] + histT[(size_t)bin*256 + b] + pos;
    dperm[dest] = i;
    mst_s[dest] = v;
}

// ---------------- exact intra-bucket sort (value, orig idx) ---------------------------
__global__ __launch_bounds__(64) void sortfix_kernel(
    float* __restrict__ mst_s, int* __restrict__ dperm,
    const unsigned int* __restrict__ gbase, const unsigned int* __restrict__ btot)
{
    __shared__ float vals[512];
    __shared__ int idxs[512];
    int b = blockIdx.x;
    int base = (int)gbase[b];
    int n = (int)btot[b];
    if (n > 512) n = 512;
    if (n <= 1) return;
    int t = threadIdx.x;
    for (int i = t; i < n; i += 64) { vals[i] = mst_s[base + i]; idxs[i] = dperm[base + i]; }
    __syncthreads();
    for (int i = t; i < n; i += 64) {
        float v = vals[i]; int d = idxs[i];
        int rank = 0;
        for (int j = 0; j < n; ++j) {
            float vj = vals[j];
            rank += (vj < v) || (vj == v && idxs[j] < d);
        }
        mst_s[base + rank] = v;
        dperm[base + rank] = d;
    }
}

// ---------------- K_B: mem_norm (0..511) || query_prep+etab (512..1024) || cq (1025..1152)
__global__ __launch_bounds__(256) void kb_kernel(
    const float* __restrict__ mx, const int* __restrict__ dperm,
    const int* __restrict__ memy,
    char* __restrict__ FK, char* __restrict__ FV, float* __restrict__ y_s,
    const float* __restrict__ feat, const float* __restrict__ keyw,
    const float* __restrict__ keyb, const float* __restrict__ msgw,
    const float* __restrict__ msgb, const float* __restrict__ yemb,
    const int* __restrict__ qrank,
    unsigned short* __restrict__ q2, float* __restrict__ a, float* __restrict__ etab,
    const float* __restrict__ seed_s, const float* __restrict__ mst_s,
    const unsigned int* __restrict__ gbase, const unsigned int* __restrict__ btot,
    int* __restrict__ cq)
{
    __shared__ __align__(16) char smpool[35328];
    const int t = threadIdx.x;
    const int blk = blockIdx.x;

    if (blk < 512) {
        // ----- mem_norm: l2norm gather -> FK/FV fragment-major + y_s -----
        unsigned short* tile = (unsigned short*)smpool;            // [128][132]
        float* rs   = (float*)(smpool + 33792);
        float* invn = (float*)(smpool + 34304);
        int* operm  = (int*)(smpool + 34816);
        const int kb0 = blk * 128;
        const int gt0 = blk * 2;

        if (t < 128) operm[t] = dperm[kb0 + t];
        __syncthreads();
        if (t < 128) y_s[kb0 + t] = (float)memy[operm[t]];

        float4 vals[16];
        #pragma unroll
        for (int i = 0; i < 16; ++i) {
            int f4 = t + 256*i;
            int row = f4 >> 5, col4 = f4 & 31;
            float4 v = *(const float4*)(mx + (size_t)operm[row]*CC + col4*4);
            vals[i] = v;
            float s = v.x*v.x + v.y*v.y + v.z*v.z + v.w*v.w;
            #pragma unroll
            for (int m2 = 1; m2 < 32; m2 <<= 1) s += __shfl_xor(s, m2, 64);
            if ((t & 31) == 0) rs[row] = s;
        }
        __syncthreads();
        if (t < 128) invn[t] = 1.0f / fmaxf(sqrtf(rs[t]), 1e-12f);
        __syncthreads();
        #pragma unroll
        for (int i = 0; i < 16; ++i) {
            int f4 = t + 256*i;
            int row = f4 >> 5, col4 = f4 & 31;
            float sc = invn[row];
            float4 v = vals[i];
            ushort4 o;
            o.x = f2bf(v.x*sc); o.y = f2bf(v.y*sc); o.z = f2bf(v.z*sc); o.w = f2bf(v.w*sc);
            *(ushort4*)&tile[row*132 + col4*4] = o;
        }
        __syncthreads();
        #pragma unroll
        for (int i = 0; i < 8; ++i) {
            int u = t + 256*i;
            int tl = u >> 10;
            int s  = (u >> 8) & 3;
            int cs = (u >> 6) & 3;
            int ln = u & 63;
            int aa = ln & 15, grp = ln >> 4;
            int row = tl*64 + ((s >> 1) << 5) + ((aa & 12) << 1) + ((s & 1) << 2) + (aa & 3);
            int col = cs*32 + grp*8;
            ushort4 p0 = *(ushort4*)&tile[row*132 + col];
            ushort4 p1 = *(ushort4*)&tile[row*132 + col + 4];
            char* dst = FK + ((size_t)(gt0 + tl)*16 + s*4 + cs)*1024 + ln*16;
            *(ushort4*)dst = p0;
            *(ushort4*)(dst + 8) = p1;
        }
        #pragma unroll
        for (int i = 0; i < 8; ++i) {
            int u = t + 256*i;
            int tl = u >> 10;
            int v2 = u & 1023;
            int sc = v2 >> 7;
            int rest = v2 & 127;
            int kk = rest >> 6;
            int ln = rest & 63;
            int c = sc*16 + (ln & 15);
            int key0 = tl*64 + kk*32 + (ln >> 4)*8;
            u32 w0 = (u32)tile[(key0+0)*132 + c] | ((u32)tile[(key0+1)*132 + c] << 16);
            u32 w1 = (u32)tile[(key0+2)*132 + c] | ((u32)tile[(key0+3)*132 + c] << 16);
            u32 w2 = (u32)tile[(key0+4)*132 + c] | ((u32)tile[(key0+5)*132 + c] << 16);
            u32 w3 = (u32)tile[(key0+6)*132 + c] | ((u32)tile[(key0+7)*132 + c] << 16);
            uint4 o; o.x = w0; o.y = w1; o.z = w2; o.w = w3;
            *(uint4*)(FV + ((size_t)(gt0 + tl)*16 + sc*2 + kk)*1024 + ln*16) = o;
        }
    } else if (blk <= 1024) {
        // ----- query_prep (+ etab on blk==1024) -----
        if (blk == 1024) {
            if (t < 128) {
                float acc0 = msgb[t], acc1 = msgb[t];
                for (int c2 = 0; c2 < 128; ++c2) {
                    float w3 = msgw[(256 + c2)*128 + t];
                    acc0 = fmaf(yemb[c2], w3, acc0);
                    acc1 = fmaf(yemb[128 + c2], w3, acc1);
                }
                etab[t] = acc0;
                etab[128 + t] = acc1;
            }
            return;
        }
        float* fl = (float*)smpool;                 // [4][128]
        float* t1 = (float*)(smpool + 2048);        // [4][128]
        const int w = t >> 6;
        const int lane = t & 63;
        const int b = (blk - 512)*4 + w;
        const int j0 = lane, j1 = lane + 64;
        float f0 = feat[b*CC + j0], f1 = feat[b*CC + j1];
        fl[w*128 + j0] = f0; fl[w*128 + j1] = f1;
        float s = f0*f0 + f1*f1;
        #pragma unroll
        for (int m2 = 1; m2 < 64; m2 <<= 1) s += __shfl_xor(s, m2, 64);
        float invn = 1.0f / fmaxf(sqrtf(s), 1e-12f);
        __syncthreads();
        float g0 = 0.f, g1 = 0.f, a0 = 0.f, a1 = 0.f;
        for (int i = 0; i < 128; ++i) {
            float x = fl[w*128 + i];
            g0 = fmaf(x, keyw[i*128 + j0], g0);
            g1 = fmaf(x, keyw[i*128 + j1], g1);
            a0 = fmaf(x, msgw[i*128 + j0], a0);
            a1 = fmaf(x, msgw[i*128 + j1], a1);
        }
        t1[w*128 + j0] = g0*invn + keyb[j0];
        t1[w*128 + j1] = g1*invn + keyb[j1];
        a[b*CC + j0] = a0;
        a[b*CC + j1] = a1;
        __syncthreads();
        float q0 = 0.f, q1 = 0.f;
        for (int c2 = 0; c2 < 128; ++c2) {
            float u = t1[w*128 + c2];
            q0 = fmaf(u, keyw[j0*128 + c2], q0);
            q1 = fmaf(u, keyw[j1*128 + c2], q1);
        }
        const float LOG2E = 1.4426950408889634f;
        int rb = qrank[b];
        q2[rb*CC + j0] = f2bf(q0 * LOG2E);
        q2[rb*CC + j1] = f2bf(q1 * LOG2E);
    } else {
        // ----- cq: 16 queries/block, 16 lanes each -----
        int qi = (blk - 1025)*16 + (t >> 4);
        int l16 = t & 15;
        float s = seed_s[qi];
        int b = bucket_of(s);
        int base = (int)gbase[b];
        int n = (int)btot[b];
        int cnt = 0;
        for (int i = l16; i < n; i += 16) cnt += (mst_s[base + i] <= s) ? 1 : 0;
        #pragma unroll
        for (int m2 = 1; m2 < 16; m2 <<= 1) cnt += __shfl_xor(cnt, m2, 64);
        if (l16 == 0) cq[qi] = base + cnt;
    }
}

// ---------------- flash attention: r18 inner loop + chunk-major XCD-contiguous order --
// Logical cells enumerated chunk-major (same-chunk cells adjacent; they read the same
// 512KB of FK/FV). Dispatch index d -> logical id = (d&7)*256 + (d>>3): the XCD
// round-robin then gives each XCD a CONTIGUOUS id slice -> each chunk's data is
// fetched into one XCD's L2 ~once (T1, bijective since 2048 = 8*256).
__global__ __launch_bounds__(256, 2) void attn_kernel(
    const char* __restrict__ FK,
    const char* __restrict__ FV,
    const unsigned short* __restrict__ q2,
    const int* __restrict__ cq,
    const float* __restrict__ y_s,
    unsigned short* __restrict__ Upart,
    float* __restrict__ lpart,
    float* __restrict__ wypart)
{
    __shared__ __align__(16) char bounce[4][4352];   // per-wave transpose bounce

    const int tid = threadIdx.x;
    const int w = tid >> 6;
    const int lane = tid & 63;
    const int g = lane >> 4;
    const int l15 = lane & 15;

    // XCD-contiguous logical id, then chunk-major decode.
    // active(c) = 32 - c/2 cells (qb in [c/2, 32)); inactive(c) = c/2 (qb in [0, c/2)).
    int qb, chunk;
    {
        int d = blockIdx.x;                        // 0..2047
        int id = (d & 7)*256 + (d >> 3);           // bijective XCD swizzle
        if (id < NACT) {
            int c = 0, base = 0;
            while (id >= base + (32 - (c >> 1))) { base += 32 - (c >> 1); ++c; }
            chunk = c; qb = (c >> 1) + (id - base);
        } else {
            int k = id - NACT;
            int c = 0;
            while (k >= (c >> 1)) { k -= (c >> 1); ++c; }
            chunk = c; qb = k;                     // inactive: exits immediately below
        }
    }

    const int cbase = chunk*KCHUNK;
    const int cqmax = cq[qb*QBS + QBS - 1];
    int ntiles = (cqmax - cbase + 63) >> 6;
    if (ntiles <= 0) return;                 // matches final's na predicate exactly
    if (ntiles > KCHUNK/64) ntiles = KCHUNK/64;

    const int qrow0 = qb*QBS + w*16;
    short8 qf[4];
    #pragma unroll
    for (int cs = 0; cs < 4; ++cs)
        qf[cs] = *(const short8*)(q2 + (size_t)(qrow0 + l15)*CC + cs*32 + g*8);
    const int cqv = cq[qrow0 + l15];
    const int g8 = g*8;

    f32x4 accU[8];
    #pragma unroll
    for (int n = 0; n < 8; ++n) accU[n] = (f32x4)0.f;
    float accl = 0.f, accw = 0.f;

    const int voff = lane * 16;      // byte offset within a 1KB fragment
    const int vyoff = g * 32;        // byte offset into y row (g8 floats)

    const int gt00 = cbase >> 6;
    for (int kt2 = 0; kt2 < ntiles; ++kt2) {
        const int kb0 = cbase + kt2*64;
        const char* Kf = FK + (size_t)(gt00 + kt2)*16384;
        const char* Vf = FV + (size_t)(gt00 + kt2)*16384;
        const float* yb = y_s + kb0;
        const int cut = cqv - kb0;

        // ---- issue all 16 K fragment loads + 4 y loads (20 in flight) ----
        short8 kf00, kf01, kf02, kf03, kf10, kf11, kf12, kf13;
        short8 kf20, kf21, kf22, kf23, kf30, kf31, kf32, kf33;
        float4 y0, y1, y2, y3;
        GL4(kf00, kf01, kf02, kf03, voff, Kf);
        GL4(kf10, kf11, kf12, kf13, voff, Kf + 4096);
        GL4(kf20, kf21, kf22, kf23, voff, Kf + 8192);
        GL4(kf30, kf31, kf32, kf33, voff, Kf + 12288);
        asm volatile("global_load_dwordx4 %0, %4, %5 offset:0\n\t"
                     "global_load_dwordx4 %1, %4, %5 offset:16\n\t"
                     "global_load_dwordx4 %2, %4, %5 offset:128\n\t"
                     "global_load_dwordx4 %3, %4, %5 offset:144"
                     : "=v"(y0), "=v"(y1), "=v"(y2), "=v"(y3)
                     : "v"(vyoff), "s"(yb));

        asm volatile("s_waitcnt vmcnt(4)" ::: "memory");   // K ready; y in flight
        __builtin_amdgcn_sched_barrier(0);

        // ---- QK: 16 MFMA ----
        f32x4 st0 = (f32x4)0.f, st1 = (f32x4)0.f, st2 = (f32x4)0.f, st3 = (f32x4)0.f;
        st0 = __builtin_amdgcn_mfma_f32_16x16x32_bf16(kf00, qf[0], st0, 0, 0, 0);
        st0 = __builtin_amdgcn_mfma_f32_16x16x32_bf16(kf01, qf[1], st0, 0, 0, 0);
        st0 = __builtin_amdgcn_mfma_f32_16x16x32_bf16(kf02, qf[2], st0, 0, 0, 0);
        st0 = __builtin_amdgcn_mfma_f32_16x16x32_bf16(kf03, qf[3], st0, 0, 0, 0);
        st1 = __builtin_amdgcn_mfma_f32_16x16x32_bf16(kf10, qf[0], st1, 0, 0, 0);
        st1 = __builtin_amdgcn_mfma_f32_16x16x32_bf16(kf11, qf[1], st1, 0, 0, 0);
        st1 = __builtin_amdgcn_mfma_f32_16x16x32_bf16(kf12, qf[2], st1, 0, 0, 0);
        st1 = __builtin_amdgcn_mfma_f32_16x16x32_bf16(kf13, qf[3], st1, 0, 0, 0);
        st2 = __builtin_amdgcn_mfma_f32_16x16x32_bf16(kf20, qf[0], st2, 0, 0, 0);
        st2 = __builtin_amdgcn_mfma_f32_16x16x32_bf16(kf21, qf[1], st2, 0, 0, 0);
        st2 = __builtin_amdgcn_mfma_f32_16x16x32_bf16(kf22, qf[2], st2, 0, 0, 0);
        st2 = __builtin_amdgcn_mfma_f32_16x16x32_bf16(kf23, qf[3], st2, 0, 0, 0);
        st3 = __builtin_amdgcn_mfma_f32_16x16x32_bf16(kf30, qf[0], st3, 0, 0, 0);
        st3 = __builtin_amdgcn_mfma_f32_16x16x32_bf16(kf31, qf[1], st3, 0, 0, 0);
        st3 = __builtin_amdgcn_mfma_f32_16x16x32_bf16(kf32, qf[2], st3, 0, 0, 0);
        st3 = __builtin_amdgcn_mfma_f32_16x16x32_bf16(kf33, qf[3], st3, 0, 0, 0);

        // ---- issue all 16 V fragment loads (K regs now dead) ----
        short8 vfa0, vfb0, vfa1, vfb1, vfa2, vfb2, vfa3, vfb3;
        short8 vfa4, vfb4, vfa5, vfb5, vfa6, vfb6, vfa7, vfb7;
        GL4(vfa0, vfb0, vfa1, vfb1, voff, Vf);
        GL4(vfa2, vfb2, vfa3, vfb3, voff, Vf + 4096);
        GL4(vfa4, vfb4, vfa5, vfb5, voff, Vf + 8192);
        GL4(vfa6, vfb6, vfa7, vfb7, voff, Vf + 12288);

        asm volatile("s_waitcnt vmcnt(16)" ::: "memory");  // y ready; V in flight
        __builtin_amdgcn_sched_barrier(0);

        // ---- P = exp2(S) masked; stats; pack bf16 in-lane (covers V latency) ----
        u32 pw[8];
        {
            const int kb_ = g8;
            float p0 = (kb_ + 0 < cut) ? exp2f(st0[0]) : 0.f;
            float p1 = (kb_ + 1 < cut) ? exp2f(st0[1]) : 0.f;
            float p2 = (kb_ + 2 < cut) ? exp2f(st0[2]) : 0.f;
            float p3 = (kb_ + 3 < cut) ? exp2f(st0[3]) : 0.f;
            accl += p0 + p1 + p2 + p3;
            accw = fmaf(p0, y0.x, fmaf(p1, y0.y, fmaf(p2, y0.z, fmaf(p3, y0.w, accw))));
            pw[0] = cvtpk(p0, p1); pw[1] = cvtpk(p2, p3);
        }
        {
            const int kb_ = g8 + 4;
            float p0 = (kb_ + 0 < cut) ? exp2f(st1[0]) : 0.f;
            float p1 = (kb_ + 1 < cut) ? exp2f(st1[1]) : 0.f;
            float p2 = (kb_ + 2 < cut) ? exp2f(st1[2]) : 0.f;
            float p3 = (kb_ + 3 < cut) ? exp2f(st1[3]) : 0.f;
            accl += p0 + p1 + p2 + p3;
            accw = fmaf(p0, y1.x, fmaf(p1, y1.y, fmaf(p2, y1.z, fmaf(p3, y1.w, accw))));
            pw[2] = cvtpk(p0, p1); pw[3] = cvtpk(p2, p3);
        }
        {
            const int kb_ = 32 + g8;
            float p0 = (kb_ + 0 < cut) ? exp2f(st2[0]) : 0.f;
            float p1 = (kb_ + 1 < cut) ? exp2f(st2[1]) : 0.f;
            float p2 = (kb_ + 2 < cut) ? exp2f(st2[2]) : 0.f;
            float p3 = (kb_ + 3 < cut) ? exp2f(st2[3]) : 0.f;
            accl += p0 + p1 + p2 + p3;
            accw = fmaf(p0, y2.x, fmaf(p1, y2.y, fmaf(p2, y2.z, fmaf(p3, y2.w, accw))));
            pw[4] = cvtpk(p0, p1); pw[5] = cvtpk(p2, p3);
        }
        {
            const int kb_ = 32 + g8 + 4;
            float p0 = (kb_ + 0 < cut) ? exp2f(st3[0]) : 0.f;
            float p1 = (kb_ + 1 < cut) ? exp2f(st3[1]) : 0.f;
            float p2 = (kb_ + 2 < cut) ? exp2f(st3[2]) : 0.f;
            float p3 = (kb_ + 3 < cut) ? exp2f(st3[3]) : 0.f;
            accl += p0 + p1 + p2 + p3;
            accw = fmaf(p0, y3.x, fmaf(p1, y3.y, fmaf(p2, y3.z, fmaf(p3, y3.w, accw))));
            pw[6] = cvtpk(p0, p1); pw[7] = cvtpk(p2, p3);
        }
        u32x4 t0v = {pw[0], pw[1], pw[2], pw[3]};
        u32x4 t1v = {pw[4], pw[5], pw[6], pw[7]};
        short8 pa0 = __builtin_bit_cast(short8, t0v);
        short8 pa1 = __builtin_bit_cast(short8, t1v);

        asm volatile("s_waitcnt vmcnt(0)" ::: "memory");   // V ready
        __builtin_amdgcn_sched_barrier(0);

        // ---- PV: 16 MFMA ----
        accU[0] = __builtin_amdgcn_mfma_f32_16x16x32_bf16(vfa0, pa0, accU[0], 0, 0, 0);
        accU[0] = __builtin_amdgcn_mfma_f32_16x16x32_bf16(vfb0, pa1, accU[0], 0, 0, 0);
        accU[1] = __builtin_amdgcn_mfma_f32_16x16x32_bf16(vfa1, pa0, accU[1], 0, 0, 0);
        accU[1] = __builtin_amdgcn_mfma_f32_16x16x32_bf16(vfb1, pa1, accU[1], 0, 0, 0);
        accU[2] = __builtin_amdgcn_mfma_f32_16x16x32_bf16(vfa2, pa0, accU[2], 0, 0, 0);
        accU[2] = __builtin_amdgcn_mfma_f32_16x16x32_bf16(vfb2, pa1, accU[2], 0, 0, 0);
        accU[3] = __builtin_amdgcn_mfma_f32_16x16x32_bf16(vfa3, pa0, accU[3], 0, 0, 0);
        accU[3] = __builtin_amdgcn_mfma_f32_16x16x32_bf16(vfb3, pa1, accU[3], 0, 0, 0);
        accU[4] = __builtin_amdgcn_mfma_f32_16x16x32_bf16(vfa4, pa0, accU[4], 0, 0, 0);
        accU[4] = __builtin_amdgcn_mfma_f32_16x16x32_bf16(vfb4, pa1, accU[4], 0, 0, 0);
        accU[5] = __builtin_amdgcn_mfma_f32_16x16x32_bf16(vfa5, pa0, accU[5], 0, 0, 0);
        accU[5] = __builtin_amdgcn_mfma_f32_16x16x32_bf16(vfb5, pa1, accU[5], 0, 0, 0);
        accU[6] = __builtin_amdgcn_mfma_f32_16x16x32_bf16(vfa6, pa0, accU[6], 0, 0, 0);
        accU[6] = __builtin_amdgcn_mfma_f32_16x16x32_bf16(vfb6, pa1, accU[6], 0, 0, 0);
        accU[7] = __builtin_amdgcn_mfma_f32_16x16x32_bf16(vfa7, pa0, accU[7], 0, 0, 0);
        accU[7] = __builtin_amdgcn_mfma_f32_16x16x32_bf16(vfb7, pa1, accU[7], 0, 0, 0);
    }

    // ---- epilogue (per-wave, no block barriers; r12-verified) ----
    const int cell = qb*NSPLIT + chunk;
    accl += __shfl_xor(accl, 16, 64); accl += __shfl_xor(accl, 32, 64);
    accw += __shfl_xor(accw, 16, 64); accw += __shfl_xor(accw, 32, 64);
    if (lane < 16) {
        lpart [cell*QBS + w*16 + lane] = accl;
        wypart[cell*QBS + w*16 + lane] = accw;
    }
    char* bw = bounce[w];
    #pragma unroll
    for (int sc = 0; sc < 8; ++sc) {
        #pragma unroll
        for (int jp = 0; jp < 2; ++jp) {
            u32 pk = cvtpk(accU[sc][2*jp], accU[sc][2*jp + 1]);
            *(u32*)(bw + l15*272 + (sc*16 + g*4 + 2*jp)*2) = pk;
        }
    }
    asm volatile("s_waitcnt lgkmcnt(0)" ::: "memory");
    __builtin_amdgcn_sched_barrier(0);
    #pragma unroll
    for (int p = 0; p < 4; ++p) {
        int seg = p*4 + (lane & 3);
        int q = lane >> 2;
        uint4 v = *(const uint4*)(bw + q*272 + seg*16);
        *(uint4*)((char*)Upart + (size_t)(cell*QBS + w*16 + q)*256 + seg*16) = v;
    }
}

// ---------------- fused combine + epilogue MLP (r18, verified) ------------------------
__global__ __launch_bounds__(256) void final_kernel(
    const float* __restrict__ feat, const unsigned short* __restrict__ Upart,
    const float* __restrict__ lpart, const float* __restrict__ wypart,
    const int* __restrict__ cq,
    const float* __restrict__ a, const float* __restrict__ etab,
    const float* __restrict__ msgw, const int* __restrict__ qperm,
    const float* __restrict__ uw1, const float* __restrict__ ub1,
    const float* __restrict__ uw2, const float* __restrict__ ub2,
    float* __restrict__ out)
{
    __shared__ float fl[4][128], t0[4][128], t1l[4][128];
    const int t = threadIdx.x;
    const int w = t >> 6;
    const int lane = t & 63;
    const int b = blockIdx.x*4 + w;      // sorted row
    const int qb = b >> 6;
    const int cqmax = cq[qb*QBS + QBS - 1];
    int na = (cqmax + KCHUNK - 1) >> 10; // KCHUNK = 1024
    if (na > NSPLIT) na = NSPLIT;        // >= 1 since key 0 always allowed
    const int ob = qperm[b];             // original row
    const int rowin = b & (QBS - 1);
    const int j0 = lane, j1 = lane + 64;
    float f0 = feat[ob*CC + j0], f1 = feat[ob*CC + j1];
    fl[w][j0] = f0; fl[w][j1] = f1;
    float lv = 0.f, wv = 0.f;
    if (lane < na) {
        int o = (qb*NSPLIT + lane)*QBS + rowin;
        lv = lpart[o]; wv = wypart[o];
    }
    #pragma unroll
    for (int m2 = 1; m2 < 64; m2 <<= 1) {
        lv += __shfl_xor(lv, m2, 64);
        wv += __shfl_xor(wv, m2, 64);
    }
    float ua = 0.f, ub = 0.f;
    for (int j = 0; j < na; ++j) {
        const unsigned short* up = Upart + (size_t)((qb*NSPLIT + j)*QBS + rowin)*CC;
        u32 pk = *(const u32*)(up + 2*lane);
        ua += bf2f((unsigned short)(pk & 0xffff));
        ub += bf2f((unsigned short)(pk >> 16));
    }
    t0[w][2*lane] = ua; t0[w][2*lane + 1] = ub;
    __syncthreads();
    float linv = 1.0f / lv;
    float s1 = wv / lv;
    float acc0 = 0.f, acc1 = 0.f;
    for (int i = 0; i < 128; ++i) {
        float x = t0[w][i];
        acc0 = fmaf(x, msgw[(128 + i)*128 + j0], acc0);
        acc1 = fmaf(x, msgw[(128 + i)*128 + j1], acc1);
    }
    float mix0 = (1.f - s1)*etab[j0] + s1*etab[128 + j0];
    float mix1 = (1.f - s1)*etab[j1] + s1*etab[128 + j1];
    float hg0 = a[ob*CC + j0] + acc0*linv + mix0;
    float hg1 = a[ob*CC + j1] + acc1*linv + mix1;
    __syncthreads();
    t0[w][j0] = hg0; t0[w][j1] = hg1;
    __syncthreads();
    float h0 = ub1[j0], h1 = ub1[j1];
    for (int i = 0; i < 128; ++i) {
        float xf = fl[w][i];
        float xh = t0[w][i];
        h0 = fmaf(xf, uw1[i*128 + j0], h0);
        h1 = fmaf(xf, uw1[i*128 + j1], h1);
        h0 = fmaf(xh, uw1[(128 + i)*128 + j0], h0);
        h1 = fmaf(xh, uw1[(128 + i)*128 + j1], h1);
    }
    h0 = fmaxf(h0, 0.f); h1 = fmaxf(h1, 0.f);
    t1l[w][j0] = h0; t1l[w][j1] = h1;
    __syncthreads();
    float o0 = ub2[j0], o1 = ub2[j1];
    for (int i = 0; i < 128; ++i) {
        float x = t1l[w][i];
        o0 = fmaf(x, uw2[i*128 + j0], o0);
        o1 = fmaf(x, uw2[i*128 + j1], o1);
    }
    out[ob*CC + j0] = f0 + o0;
    out[ob*CC + j1] = f1 + o1;
}

extern "C" void kernel_launch(void* const* d_in, const int* in_sizes, int n_in,
                              void* d_out, int out_size, void* d_ws, size_t ws_size,
                              hipStream_t stream) {
    (void)in_sizes; (void)n_in; (void)out_size; (void)ws_size;
    const float* feature  = (const float*)d_in[0];
    const float* memory_x = (const float*)d_in[1];
    const int*   memory_y = (const int*)d_in[2];
    const float* seed_t   = (const float*)d_in[3];
    const float* mem_st   = (const float*)d_in[4];
    const float* key_w    = (const float*)d_in[5];
    const float* key_b    = (const float*)d_in[6];
    const float* msg_w    = (const float*)d_in[7];
    const float* msg_b    = (const float*)d_in[8];
    const float* upd_w1   = (const float*)d_in[9];
    const float* upd_b1   = (const float*)d_in[10];
    const float* upd_w2   = (const float*)d_in[11];
    const float* upd_b2   = (const float*)d_in[12];
    const float* y_emb    = (const float*)d_in[13];
    float* out = (float*)d_out;

    // ---- bump-allocated workspace (256B aligned) ----
    char* ws = (char*)d_ws;
    size_t off = 0;
    auto A = [&](size_t bytes) -> char* {
        char* p = ws + off;
        off += (bytes + 255) & ~(size_t)255;
        return p;
    };
    char* FK = A((size_t)(MM/64)*16*1024);                               // 16.78 MB
    char* FV = A((size_t)(MM/64)*16*1024);                               // 16.78 MB
    unsigned short* q2    = (unsigned short*)A((size_t)BQ*CC*2);         // 512 KB
    float* a      = (float*)A((size_t)BQ*CC*4);                          // 1 MB
    float* etab   = (float*)A(2*CC*4);
    float* lpart  = (float*)A((size_t)NQB*NSPLIT*QBS*4);                 // 512 KB
    float* wypart = (float*)A((size_t)NQB*NSPLIT*QBS*4);                 // 512 KB
    int*   dperm  = (int*)A((size_t)MM*4);                               // 256 KB
    float* mst_s  = (float*)A((size_t)MM*4);                             // 256 KB
    float* y_s    = (float*)A((size_t)MM*4);                             // 256 KB
    unsigned int* btot  = (unsigned int*)A(NBUCKET*4);
    unsigned int* gbase = (unsigned int*)A(NBUCKET*4);
    int*   qperm  = (int*)A(BQ*4);
    int*   qrank  = (int*)A(BQ*4);
    float* seed_s = (float*)A(BQ*4);
    int*   cqbuf  = (int*)A(BQ*4);
    unsigned int* histT = (unsigned int*)A((size_t)NBUCKET*256*4);       // 1 MB
    unsigned short* Upart = (unsigned short*)A((size_t)NQB*NSPLIT*QBS*CC*2); // 33.5 MB

    ka_kernel<<<512, 256, 0, stream>>>(seed_t, mem_st, qperm, qrank, seed_s, histT);
    sort_scanA_kernel<<<NBUCKET, 64, 0, stream>>>(histT, btot);
    sort_scanB_kernel<<<1, 1024, 0, stream>>>(btot, gbase);
    sort_scatter_kernel<<<MM/256, 256, 0, stream>>>(mem_st, histT, gbase, dperm, mst_s);
    sortfix_kernel<<<NBUCKET, 64, 0, stream>>>(mst_s, dperm, gbase, btot);
    kb_kernel<<<1153, 256, 0, stream>>>(memory_x, dperm, memory_y, FK, FV, y_s,
                                        feature, key_w, key_b, msg_w, msg_b, y_emb,
                                        qrank, q2, a, etab,
                                        seed_s, mst_s, gbase, btot, cqbuf);
    attn_kernel<<<NQB*NSPLIT, 256, 0, stream>>>(FK, FV, q2, cqbuf, y_s,
                                                Upart, lpart, wypart);
    final_kernel<<<BQ/4, 256, 0, stream>>>(feature, Upart, lpart, wypart, cqbuf,
                                           a, etab, msg_w, qperm,
                                           upd_w1, upd_b1, upd_w2, upd_b2, out);
}

// Round 25
// 191.921 us; speedup vs baseline: 3.6334x; 1.2838x over previous
//
#include <hip/hip_runtime.h>

#define BQ 2048
#define MM 65536
#define CC 128
#define QBS 64
#define NQB 32
#define NSPLIT 64
#define KCHUNK (MM/NSPLIT)      // 1024
#define NBUCKET 1024

typedef short short8 __attribute__((ext_vector_type(8)));
typedef float f32x4 __attribute__((ext_vector_type(4)));
typedef unsigned int u32x4 __attribute__((ext_vector_type(4)));
typedef unsigned int u32;

__device__ __forceinline__ unsigned short f2bf(float x) {
    unsigned int u = __builtin_bit_cast(unsigned int, x);
    u = (u + 0x7FFFu + ((u >> 16) & 1u)) >> 16;
    return (unsigned short)u;
}
__device__ __forceinline__ float bf2f(unsigned short u) {
    return __builtin_bit_cast(float, (unsigned int)u << 16);
}
__device__ __forceinline__ int bucket_of(float v) {
    return (int)fminf(fmaxf(v * 1024.0f, 0.0f), 1023.0f);
}
__device__ __forceinline__ u32 cvtpk(float lo, float hi) {
    u32 r;
    asm("v_cvt_pk_bf16_f32 %0, %1, %2" : "=v"(r) : "v"(lo), "v"(hi));
    return r;
}

// 4 coalesced 1KB fragment loads, one asm block (volatile: compiler cannot sink/split)
#define GL4(d0, d1, d2, d3, off, base)                                    \
    asm volatile("global_load_dwordx4 %0, %4, %5 offset:0\n\t"            \
                 "global_load_dwordx4 %1, %4, %5 offset:1024\n\t"         \
                 "global_load_dwordx4 %2, %4, %5 offset:2048\n\t"         \
                 "global_load_dwordx4 %3, %4, %5 offset:3072"             \
                 : "=v"(d0), "=v"(d1), "=v"(d2), "=v"(d3)                 \
                 : "v"(off), "s"(base))

// ---------------- K_A: qrank (blocks 0..255)  ||  hist (blocks 256..511) -------------
__global__ __launch_bounds__(256) void ka_kernel(
    const float* __restrict__ seed, const float* __restrict__ mst,
    int* __restrict__ qperm, int* __restrict__ qrank, float* __restrict__ seed_s,
    unsigned int* __restrict__ histT)
{
    __shared__ unsigned int h[NBUCKET];
    int t = threadIdx.x;
    if (blockIdx.x < 256) {
        int q = blockIdx.x*8 + (t >> 5);
        int l32 = t & 31;
        float v = seed[q];
        int r = 0;
        for (int seg = 0; seg < 64; ++seg) {
            int j = seg*32 + l32;
            float u = seed[j];
            r += (u < v) || (u == v && j < q);
        }
        #pragma unroll
        for (int m2 = 1; m2 < 32; m2 <<= 1) r += __shfl_xor(r, m2, 32);
        if (l32 == 0) { qperm[r] = q; qrank[q] = r; seed_s[r] = v; }
    } else {
        int b = blockIdx.x - 256;
        #pragma unroll
        for (int j = t; j < NBUCKET; j += 256) h[j] = 0;
        __syncthreads();
        int bin = bucket_of(mst[b*256 + t]);
        atomicAdd(&h[bin], 1u);
        __syncthreads();
        #pragma unroll
        for (int j = t; j < NBUCKET; j += 256) histT[(size_t)j*256 + b] = h[j];
    }
}

__global__ __launch_bounds__(64) void sort_scanA_kernel(
    unsigned int* __restrict__ histT, unsigned int* __restrict__ btot)
{
    int j = blockIdx.x;
    int t = threadIdx.x;
    uint4 v = *(uint4*)(histT + (size_t)j*256 + t*4);
    unsigned int s0 = v.x, s1 = v.y, s2 = v.z, s3 = v.w;
    unsigned int tsum = s0 + s1 + s2 + s3;
    unsigned int inc = tsum;
    #pragma unroll
    for (int off = 1; off < 64; off <<= 1) {
        unsigned int n = __shfl_up(inc, off, 64);
        if (t >= off) inc += n;
    }
    unsigned int ex = inc - tsum;
    uint4 o;
    o.x = ex; o.y = ex + s0; o.z = ex + s0 + s1; o.w = ex + s0 + s1 + s2;
    *(uint4*)(histT + (size_t)j*256 + t*4) = o;
    if (t == 63) btot[j] = inc;
}

__global__ __launch_bounds__(1024) void sort_scanB_kernel(
    const unsigned int* __restrict__ btot, unsigned int* __restrict__ gbase)
{
    __shared__ unsigned int sc[NBUCKET];
    int j = threadIdx.x;
    unsigned int tot = btot[j];
    sc[j] = tot;
    __syncthreads();
    for (int off = 1; off < NBUCKET; off <<= 1) {
        unsigned int y = (j >= off) ? sc[j - off] : 0u;
        __syncthreads();
        sc[j] += y;
        __syncthreads();
    }
    gbase[j] = sc[j] - tot;
}

__global__ __launch_bounds__(256) void sort_scatter_kernel(
    const float* __restrict__ mst, const unsigned int* __restrict__ histT,
    const unsigned int* __restrict__ gbase,
    int* __restrict__ dperm, float* __restrict__ mst_s)
{
    __shared__ int bins[256];
    int t = threadIdx.x, b = blockIdx.x;
    int i = b*256 + t;
    float v = mst[i];
    int bin = bucket_of(v);
    bins[t] = bin;
    __syncthreads();
    int pos = 0;
    for (int j = 0; j < t; ++j) pos += (bins[j] == bin);
    unsigned int dest = gbase[bin] + histT[(size_t)bin*256 + b] + pos;
    dperm[dest] = i;
    mst_s[dest] = v;
}

// ---------------- exact intra-bucket sort (value, orig idx) ---------------------------
__global__ __launch_bounds__(64) void sortfix_kernel(
    float* __restrict__ mst_s, int* __restrict__ dperm,
    const unsigned int* __restrict__ gbase, const unsigned int* __restrict__ btot)
{
    __shared__ float vals[512];
    __shared__ int idxs[512];
    int b = blockIdx.x;
    int base = (int)gbase[b];
    int n = (int)btot[b];
    if (n > 512) n = 512;
    if (n <= 1) return;
    int t = threadIdx.x;
    for (int i = t; i < n; i += 64) { vals[i] = mst_s[base + i]; idxs[i] = dperm[base + i]; }
    __syncthreads();
    for (int i = t; i < n; i += 64) {
        float v = vals[i]; int d = idxs[i];
        int rank = 0;
        for (int j = 0; j < n; ++j) {
            float vj = vals[j];
            rank += (vj < v) || (vj == v && idxs[j] < d);
        }
        mst_s[base + rank] = v;
        dperm[base + rank] = d;
    }
}

// ---------------- K_B: mem_norm (0..511) || query_prep+etab (512..1024) || cq (1025..1152)
__global__ __launch_bounds__(256) void kb_kernel(
    const float* __restrict__ mx, const int* __restrict__ dperm,
    const int* __restrict__ memy,
    char* __restrict__ FK, char* __restrict__ FV, float* __restrict__ y_s,
    const float* __restrict__ feat, const float* __restrict__ keyw,
    const float* __restrict__ keyb, const float* __restrict__ msgw,
    const float* __restrict__ msgb, const float* __restrict__ yemb,
    const int* __restrict__ qrank,
    unsigned short* __restrict__ q2, float* __restrict__ a, float* __restrict__ etab,
    const float* __restrict__ seed_s, const float* __restrict__ mst_s,
    const unsigned int* __restrict__ gbase, const unsigned int* __restrict__ btot,
    int* __restrict__ cq)
{
    __shared__ __align__(16) char smpool[35328];
    const int t = threadIdx.x;
    const int blk = blockIdx.x;

    if (blk < 512) {
        // ----- mem_norm: l2norm gather -> FK/FV fragment-major + y_s -----
        unsigned short* tile = (unsigned short*)smpool;            // [128][132]
        float* rs   = (float*)(smpool + 33792);
        float* invn = (float*)(smpool + 34304);
        int* operm  = (int*)(smpool + 34816);
        const int kb0 = blk * 128;
        const int gt0 = blk * 2;

        if (t < 128) operm[t] = dperm[kb0 + t];
        __syncthreads();
        if (t < 128) y_s[kb0 + t] = (float)memy[operm[t]];

        float4 vals[16];
        #pragma unroll
        for (int i = 0; i < 16; ++i) {
            int f4 = t + 256*i;
            int row = f4 >> 5, col4 = f4 & 31;
            float4 v = *(const float4*)(mx + (size_t)operm[row]*CC + col4*4);
            vals[i] = v;
            float s = v.x*v.x + v.y*v.y + v.z*v.z + v.w*v.w;
            #pragma unroll
            for (int m2 = 1; m2 < 32; m2 <<= 1) s += __shfl_xor(s, m2, 64);
            if ((t & 31) == 0) rs[row] = s;
        }
        __syncthreads();
        if (t < 128) invn[t] = 1.0f / fmaxf(sqrtf(rs[t]), 1e-12f);
        __syncthreads();
        #pragma unroll
        for (int i = 0; i < 16; ++i) {
            int f4 = t + 256*i;
            int row = f4 >> 5, col4 = f4 & 31;
            float sc = invn[row];
            float4 v = vals[i];
            ushort4 o;
            o.x = f2bf(v.x*sc); o.y = f2bf(v.y*sc); o.z = f2bf(v.z*sc); o.w = f2bf(v.w*sc);
            *(ushort4*)&tile[row*132 + col4*4] = o;
        }
        __syncthreads();
        #pragma unroll
        for (int i = 0; i < 8; ++i) {
            int u = t + 256*i;
            int tl = u >> 10;
            int s  = (u >> 8) & 3;
            int cs = (u >> 6) & 3;
            int ln = u & 63;
            int aa = ln & 15, grp = ln >> 4;
            int row = tl*64 + ((s >> 1) << 5) + ((aa & 12) << 1) + ((s & 1) << 2) + (aa & 3);
            int col = cs*32 + grp*8;
            ushort4 p0 = *(ushort4*)&tile[row*132 + col];
            ushort4 p1 = *(ushort4*)&tile[row*132 + col + 4];
            char* dst = FK + ((size_t)(gt0 + tl)*16 + s*4 + cs)*1024 + ln*16;
            *(ushort4*)dst = p0;
            *(ushort4*)(dst + 8) = p1;
        }
        #pragma unroll
        for (int i = 0; i < 8; ++i) {
            int u = t + 256*i;
            int tl = u >> 10;
            int v2 = u & 1023;
            int sc = v2 >> 7;
            int rest = v2 & 127;
            int kk = rest >> 6;
            int ln = rest & 63;
            int c = sc*16 + (ln & 15);
            int key0 = tl*64 + kk*32 + (ln >> 4)*8;
            u32 w0 = (u32)tile[(key0+0)*132 + c] | ((u32)tile[(key0+1)*132 + c] << 16);
            u32 w1 = (u32)tile[(key0+2)*132 + c] | ((u32)tile[(key0+3)*132 + c] << 16);
            u32 w2 = (u32)tile[(key0+4)*132 + c] | ((u32)tile[(key0+5)*132 + c] << 16);
            u32 w3 = (u32)tile[(key0+6)*132 + c] | ((u32)tile[(key0+7)*132 + c] << 16);
            uint4 o; o.x = w0; o.y = w1; o.z = w2; o.w = w3;
            *(uint4*)(FV + ((size_t)(gt0 + tl)*16 + sc*2 + kk)*1024 + ln*16) = o;
        }
    } else if (blk <= 1024) {
        // ----- query_prep (+ etab on blk==1024) -----
        if (blk == 1024) {
            if (t < 128) {
                float acc0 = msgb[t], acc1 = msgb[t];
                for (int c2 = 0; c2 < 128; ++c2) {
                    float w3 = msgw[(256 + c2)*128 + t];
                    acc0 = fmaf(yemb[c2], w3, acc0);
                    acc1 = fmaf(yemb[128 + c2], w3, acc1);
                }
                etab[t] = acc0;
                etab[128 + t] = acc1;
            }
            return;
        }
        float* fl = (float*)smpool;                 // [4][128]
        float* t1 = (float*)(smpool + 2048);        // [4][128]
        const int w = t >> 6;
        const int lane = t & 63;
        const int b = (blk - 512)*4 + w;
        const int j0 = lane, j1 = lane + 64;
        float f0 = feat[b*CC + j0], f1 = feat[b*CC + j1];
        fl[w*128 + j0] = f0; fl[w*128 + j1] = f1;
        float s = f0*f0 + f1*f1;
        #pragma unroll
        for (int m2 = 1; m2 < 64; m2 <<= 1) s += __shfl_xor(s, m2, 64);
        float invn = 1.0f / fmaxf(sqrtf(s), 1e-12f);
        __syncthreads();
        float g0 = 0.f, g1 = 0.f, a0 = 0.f, a1 = 0.f;
        for (int i = 0; i < 128; ++i) {
            float x = fl[w*128 + i];
            g0 = fmaf(x, keyw[i*128 + j0], g0);
            g1 = fmaf(x, keyw[i*128 + j1], g1);
            a0 = fmaf(x, msgw[i*128 + j0], a0);
            a1 = fmaf(x, msgw[i*128 + j1], a1);
        }
        t1[w*128 + j0] = g0*invn + keyb[j0];
        t1[w*128 + j1] = g1*invn + keyb[j1];
        a[b*CC + j0] = a0;
        a[b*CC + j1] = a1;
        __syncthreads();
        float q0 = 0.f, q1 = 0.f;
        for (int c2 = 0; c2 < 128; ++c2) {
            float u = t1[w*128 + c2];
            q0 = fmaf(u, keyw[j0*128 + c2], q0);
            q1 = fmaf(u, keyw[j1*128 + c2], q1);
        }
        const float LOG2E = 1.4426950408889634f;
        int rb = qrank[b];
        q2[rb*CC + j0] = f2bf(q0 * LOG2E);
        q2[rb*CC + j1] = f2bf(q1 * LOG2E);
    } else {
        // ----- cq: 16 queries/block, 16 lanes each -----
        int qi = (blk - 1025)*16 + (t >> 4);
        int l16 = t & 15;
        float s = seed_s[qi];
        int b = bucket_of(s);
        int base = (int)gbase[b];
        int n = (int)btot[b];
        int cnt = 0;
        for (int i = l16; i < n; i += 16) cnt += (mst_s[base + i] <= s) ? 1 : 0;
        #pragma unroll
        for (int m2 = 1; m2 < 16; m2 <<= 1) cnt += __shfl_xor(cnt, m2, 64);
        if (l16 == 0) cq[qi] = base + cnt;
    }
}

// ---------------- flash attention: r18 inner loop + chunk->XCD modular assignment -----
// chunk c handled by XCD (c&7): dispatch d -> xcd = d&7, chunk = xcd + ((d>>3)>>5)*8,
// qb = (d>>3)&31. Each XCD owns 8 whole chunks (same-chunk cells adjacent, ~1MB live
// working set in its 4MB L2) AND all 8 XCDs carry active work (balance fix for r24).
__global__ __launch_bounds__(256, 2) void attn_kernel(
    const char* __restrict__ FK,
    const char* __restrict__ FV,
    const unsigned short* __restrict__ q2,
    const int* __restrict__ cq,
    const float* __restrict__ y_s,
    unsigned short* __restrict__ Upart,
    float* __restrict__ lpart,
    float* __restrict__ wypart)
{
    __shared__ __align__(16) char bounce[4][4352];   // per-wave transpose bounce

    const int tid = threadIdx.x;
    const int w = tid >> 6;
    const int lane = tid & 63;
    const int g = lane >> 4;
    const int l15 = lane & 15;

    // chunk->XCD modular decode (balanced + L2-local)
    int qb, chunk;
    {
        int d = blockIdx.x;              // 0..2047
        int xcd = d & 7;
        int j = d >> 3;                  // 0..255
        chunk = xcd + (j >> 5)*8;        // 8 chunks per XCD
        qb = j & 31;
    }

    const int cbase = chunk*KCHUNK;
    const int cqmax = cq[qb*QBS + QBS - 1];
    int ntiles = (cqmax - cbase + 63) >> 6;
    if (ntiles <= 0) return;                 // matches final's na predicate exactly
    if (ntiles > KCHUNK/64) ntiles = KCHUNK/64;

    const int qrow0 = qb*QBS + w*16;
    short8 qf[4];
    #pragma unroll
    for (int cs = 0; cs < 4; ++cs)
        qf[cs] = *(const short8*)(q2 + (size_t)(qrow0 + l15)*CC + cs*32 + g*8);
    const int cqv = cq[qrow0 + l15];
    const int g8 = g*8;

    f32x4 accU[8];
    #pragma unroll
    for (int n = 0; n < 8; ++n) accU[n] = (f32x4)0.f;
    float accl = 0.f, accw = 0.f;

    const int voff = lane * 16;      // byte offset within a 1KB fragment
    const int vyoff = g * 32;        // byte offset into y row (g8 floats)

    const int gt00 = cbase >> 6;
    for (int kt2 = 0; kt2 < ntiles; ++kt2) {
        const int kb0 = cbase + kt2*64;
        const char* Kf = FK + (size_t)(gt00 + kt2)*16384;
        const char* Vf = FV + (size_t)(gt00 + kt2)*16384;
        const float* yb = y_s + kb0;
        const int cut = cqv - kb0;

        // ---- issue all 16 K fragment loads + 4 y loads (20 in flight) ----
        short8 kf00, kf01, kf02, kf03, kf10, kf11, kf12, kf13;
        short8 kf20, kf21, kf22, kf23, kf30, kf31, kf32, kf33;
        float4 y0, y1, y2, y3;
        GL4(kf00, kf01, kf02, kf03, voff, Kf);
        GL4(kf10, kf11, kf12, kf13, voff, Kf + 4096);
        GL4(kf20, kf21, kf22, kf23, voff, Kf + 8192);
        GL4(kf30, kf31, kf32, kf33, voff, Kf + 12288);
        asm volatile("global_load_dwordx4 %0, %4, %5 offset:0\n\t"
                     "global_load_dwordx4 %1, %4, %5 offset:16\n\t"
                     "global_load_dwordx4 %2, %4, %5 offset:128\n\t"
                     "global_load_dwordx4 %3, %4, %5 offset:144"
                     : "=v"(y0), "=v"(y1), "=v"(y2), "=v"(y3)
                     : "v"(vyoff), "s"(yb));

        asm volatile("s_waitcnt vmcnt(4)" ::: "memory");   // K ready; y in flight
        __builtin_amdgcn_sched_barrier(0);

        // ---- QK: 16 MFMA ----
        f32x4 st0 = (f32x4)0.f, st1 = (f32x4)0.f, st2 = (f32x4)0.f, st3 = (f32x4)0.f;
        st0 = __builtin_amdgcn_mfma_f32_16x16x32_bf16(kf00, qf[0], st0, 0, 0, 0);
        st0 = __builtin_amdgcn_mfma_f32_16x16x32_bf16(kf01, qf[1], st0, 0, 0, 0);
        st0 = __builtin_amdgcn_mfma_f32_16x16x32_bf16(kf02, qf[2], st0, 0, 0, 0);
        st0 = __builtin_amdgcn_mfma_f32_16x16x32_bf16(kf03, qf[3], st0, 0, 0, 0);
        st1 = __builtin_amdgcn_mfma_f32_16x16x32_bf16(kf10, qf[0], st1, 0, 0, 0);
        st1 = __builtin_amdgcn_mfma_f32_16x16x32_bf16(kf11, qf[1], st1, 0, 0, 0);
        st1 = __builtin_amdgcn_mfma_f32_16x16x32_bf16(kf12, qf[2], st1, 0, 0, 0);
        st1 = __builtin_amdgcn_mfma_f32_16x16x32_bf16(kf13, qf[3], st1, 0, 0, 0);
        st2 = __builtin_amdgcn_mfma_f32_16x16x32_bf16(kf20, qf[0], st2, 0, 0, 0);
        st2 = __builtin_amdgcn_mfma_f32_16x16x32_bf16(kf21, qf[1], st2, 0, 0, 0);
        st2 = __builtin_amdgcn_mfma_f32_16x16x32_bf16(kf22, qf[2], st2, 0, 0, 0);
        st2 = __builtin_amdgcn_mfma_f32_16x16x32_bf16(kf23, qf[3], st2, 0, 0, 0);
        st3 = __builtin_amdgcn_mfma_f32_16x16x32_bf16(kf30, qf[0], st3, 0, 0, 0);
        st3 = __builtin_amdgcn_mfma_f32_16x16x32_bf16(kf31, qf[1], st3, 0, 0, 0);
        st3 = __builtin_amdgcn_mfma_f32_16x16x32_bf16(kf32, qf[2], st3, 0, 0, 0);
        st3 = __builtin_amdgcn_mfma_f32_16x16x32_bf16(kf33, qf[3], st3, 0, 0, 0);

        // ---- issue all 16 V fragment loads (K regs now dead) ----
        short8 vfa0, vfb0, vfa1, vfb1, vfa2, vfb2, vfa3, vfb3;
        short8 vfa4, vfb4, vfa5, vfb5, vfa6, vfb6, vfa7, vfb7;
        GL4(vfa0, vfb0, vfa1, vfb1, voff, Vf);
        GL4(vfa2, vfb2, vfa3, vfb3, voff, Vf + 4096);
        GL4(vfa4, vfb4, vfa5, vfb5, voff, Vf + 8192);
        GL4(vfa6, vfb6, vfa7, vfb7, voff, Vf + 12288);

        asm volatile("s_waitcnt vmcnt(16)" ::: "memory");  // y ready; V in flight
        __builtin_amdgcn_sched_barrier(0);

        // ---- P = exp2(S) masked; stats; pack bf16 in-lane (covers V latency) ----
        u32 pw[8];
        {
            const int kb_ = g8;
            float p0 = (kb_ + 0 < cut) ? exp2f(st0[0]) : 0.f;
            float p1 = (kb_ + 1 < cut) ? exp2f(st0[1]) : 0.f;
            float p2 = (kb_ + 2 < cut) ? exp2f(st0[2]) : 0.f;
            float p3 = (kb_ + 3 < cut) ? exp2f(st0[3]) : 0.f;
            accl += p0 + p1 + p2 + p3;
            accw = fmaf(p0, y0.x, fmaf(p1, y0.y, fmaf(p2, y0.z, fmaf(p3, y0.w, accw))));
            pw[0] = cvtpk(p0, p1); pw[1] = cvtpk(p2, p3);
        }
        {
            const int kb_ = g8 + 4;
            float p0 = (kb_ + 0 < cut) ? exp2f(st1[0]) : 0.f;
            float p1 = (kb_ + 1 < cut) ? exp2f(st1[1]) : 0.f;
            float p2 = (kb_ + 2 < cut) ? exp2f(st1[2]) : 0.f;
            float p3 = (kb_ + 3 < cut) ? exp2f(st1[3]) : 0.f;
            accl += p0 + p1 + p2 + p3;
            accw = fmaf(p0, y1.x, fmaf(p1, y1.y, fmaf(p2, y1.z, fmaf(p3, y1.w, accw))));
            pw[2] = cvtpk(p0, p1); pw[3] = cvtpk(p2, p3);
        }
        {
            const int kb_ = 32 + g8;
            float p0 = (kb_ + 0 < cut) ? exp2f(st2[0]) : 0.f;
            float p1 = (kb_ + 1 < cut) ? exp2f(st2[1]) : 0.f;
            float p2 = (kb_ + 2 < cut) ? exp2f(st2[2]) : 0.f;
            float p3 = (kb_ + 3 < cut) ? exp2f(st2[3]) : 0.f;
            accl += p0 + p1 + p2 + p3;
            accw = fmaf(p0, y2.x, fmaf(p1, y2.y, fmaf(p2, y2.z, fmaf(p3, y2.w, accw))));
            pw[4] = cvtpk(p0, p1); pw[5] = cvtpk(p2, p3);
        }
        {
            const int kb_ = 32 + g8 + 4;
            float p0 = (kb_ + 0 < cut) ? exp2f(st3[0]) : 0.f;
            float p1 = (kb_ + 1 < cut) ? exp2f(st3[1]) : 0.f;
            float p2 = (kb_ + 2 < cut) ? exp2f(st3[2]) : 0.f;
            float p3 = (kb_ + 3 < cut) ? exp2f(st3[3]) : 0.f;
            accl += p0 + p1 + p2 + p3;
            accw = fmaf(p0, y3.x, fmaf(p1, y3.y, fmaf(p2, y3.z, fmaf(p3, y3.w, accw))));
            pw[6] = cvtpk(p0, p1); pw[7] = cvtpk(p2, p3);
        }
        u32x4 t0v = {pw[0], pw[1], pw[2], pw[3]};
        u32x4 t1v = {pw[4], pw[5], pw[6], pw[7]};
        short8 pa0 = __builtin_bit_cast(short8, t0v);
        short8 pa1 = __builtin_bit_cast(short8, t1v);

        asm volatile("s_waitcnt vmcnt(0)" ::: "memory");   // V ready
        __builtin_amdgcn_sched_barrier(0);

        // ---- PV: 16 MFMA ----
        accU[0] = __builtin_amdgcn_mfma_f32_16x16x32_bf16(vfa0, pa0, accU[0], 0, 0, 0);
        accU[0] = __builtin_amdgcn_mfma_f32_16x16x32_bf16(vfb0, pa1, accU[0], 0, 0, 0);
        accU[1] = __builtin_amdgcn_mfma_f32_16x16x32_bf16(vfa1, pa0, accU[1], 0, 0, 0);
        accU[1] = __builtin_amdgcn_mfma_f32_16x16x32_bf16(vfb1, pa1, accU[1], 0, 0, 0);
        accU[2] = __builtin_amdgcn_mfma_f32_16x16x32_bf16(vfa2, pa0, accU[2], 0, 0, 0);
        accU[2] = __builtin_amdgcn_mfma_f32_16x16x32_bf16(vfb2, pa1, accU[2], 0, 0, 0);
        accU[3] = __builtin_amdgcn_mfma_f32_16x16x32_bf16(vfa3, pa0, accU[3], 0, 0, 0);
        accU[3] = __builtin_amdgcn_mfma_f32_16x16x32_bf16(vfb3, pa1, accU[3], 0, 0, 0);
        accU[4] = __builtin_amdgcn_mfma_f32_16x16x32_bf16(vfa4, pa0, accU[4], 0, 0, 0);
        accU[4] = __builtin_amdgcn_mfma_f32_16x16x32_bf16(vfb4, pa1, accU[4], 0, 0, 0);
        accU[5] = __builtin_amdgcn_mfma_f32_16x16x32_bf16(vfa5, pa0, accU[5], 0, 0, 0);
        accU[5] = __builtin_amdgcn_mfma_f32_16x16x32_bf16(vfb5, pa1, accU[5], 0, 0, 0);
        accU[6] = __builtin_amdgcn_mfma_f32_16x16x32_bf16(vfa6, pa0, accU[6], 0, 0, 0);
        accU[6] = __builtin_amdgcn_mfma_f32_16x16x32_bf16(vfb6, pa1, accU[6], 0, 0, 0);
        accU[7] = __builtin_amdgcn_mfma_f32_16x16x32_bf16(vfa7, pa0, accU[7], 0, 0, 0);
        accU[7] = __builtin_amdgcn_mfma_f32_16x16x32_bf16(vfb7, pa1, accU[7], 0, 0, 0);
    }

    // ---- epilogue (per-wave, no block barriers; r12-verified) ----
    const int cell = qb*NSPLIT + chunk;
    accl += __shfl_xor(accl, 16, 64); accl += __shfl_xor(accl, 32, 64);
    accw += __shfl_xor(accw, 16, 64); accw += __shfl_xor(accw, 32, 64);
    if (lane < 16) {
        lpart [cell*QBS + w*16 + lane] = accl;
        wypart[cell*QBS + w*16 + lane] = accw;
    }
    char* bw = bounce[w];
    #pragma unroll
    for (int sc = 0; sc < 8; ++sc) {
        #pragma unroll
        for (int jp = 0; jp < 2; ++jp) {
            u32 pk = cvtpk(accU[sc][2*jp], accU[sc][2*jp + 1]);
            *(u32*)(bw + l15*272 + (sc*16 + g*4 + 2*jp)*2) = pk;
        }
    }
    asm volatile("s_waitcnt lgkmcnt(0)" ::: "memory");
    __builtin_amdgcn_sched_barrier(0);
    #pragma unroll
    for (int p = 0; p < 4; ++p) {
        int seg = p*4 + (lane & 3);
        int q = lane >> 2;
        uint4 v = *(const uint4*)(bw + q*272 + seg*16);
        *(uint4*)((char*)Upart + (size_t)(cell*QBS + w*16 + q)*256 + seg*16) = v;
    }
}

// ---------------- fused combine + epilogue MLP (r18, verified) ------------------------
__global__ __launch_bounds__(256) void final_kernel(
    const float* __restrict__ feat, const unsigned short* __restrict__ Upart,
    const float* __restrict__ lpart, const float* __restrict__ wypart,
    const int* __restrict__ cq,
    const float* __restrict__ a, const float* __restrict__ etab,
    const float* __restrict__ msgw, const int* __restrict__ qperm,
    const float* __restrict__ uw1, const float* __restrict__ ub1,
    const float* __restrict__ uw2, const float* __restrict__ ub2,
    float* __restrict__ out)
{
    __shared__ float fl[4][128], t0[4][128], t1l[4][128];
    const int t = threadIdx.x;
    const int w = t >> 6;
    const int lane = t & 63;
    const int b = blockIdx.x*4 + w;      // sorted row
    const int qb = b >> 6;
    const int cqmax = cq[qb*QBS + QBS - 1];
    int na = (cqmax + KCHUNK - 1) >> 10; // KCHUNK = 1024
    if (na > NSPLIT) na = NSPLIT;        // >= 1 since key 0 always allowed
    const int ob = qperm[b];             // original row
    const int rowin = b & (QBS - 1);
    const int j0 = lane, j1 = lane + 64;
    float f0 = feat[ob*CC + j0], f1 = feat[ob*CC + j1];
    fl[w][j0] = f0; fl[w][j1] = f1;
    float lv = 0.f, wv = 0.f;
    if (lane < na) {
        int o = (qb*NSPLIT + lane)*QBS + rowin;
        lv = lpart[o]; wv = wypart[o];
    }
    #pragma unroll
    for (int m2 = 1; m2 < 64; m2 <<= 1) {
        lv += __shfl_xor(lv, m2, 64);
        wv += __shfl_xor(wv, m2, 64);
    }
    float ua = 0.f, ub = 0.f;
    for (int j = 0; j < na; ++j) {
        const unsigned short* up = Upart + (size_t)((qb*NSPLIT + j)*QBS + rowin)*CC;
        u32 pk = *(const u32*)(up + 2*lane);
        ua += bf2f((unsigned short)(pk & 0xffff));
        ub += bf2f((unsigned short)(pk >> 16));
    }
    t0[w][2*lane] = ua; t0[w][2*lane + 1] = ub;
    __syncthreads();
    float linv = 1.0f / lv;
    float s1 = wv / lv;
    float acc0 = 0.f, acc1 = 0.f;
    for (int i = 0; i < 128; ++i) {
        float x = t0[w][i];
        acc0 = fmaf(x, msgw[(128 + i)*128 + j0], acc0);
        acc1 = fmaf(x, msgw[(128 + i)*128 + j1], acc1);
    }
    float mix0 = (1.f - s1)*etab[j0] + s1*etab[128 + j0];
    float mix1 = (1.f - s1)*etab[j1] + s1*etab[128 + j1];
    float hg0 = a[ob*CC + j0] + acc0*linv + mix0;
    float hg1 = a[ob*CC + j1] + acc1*linv + mix1;
    __syncthreads();
    t0[w][j0] = hg0; t0[w][j1] = hg1;
    __syncthreads();
    float h0 = ub1[j0], h1 = ub1[j1];
    for (int i = 0; i < 128; ++i) {
        float xf = fl[w][i];
        float xh = t0[w][i];
        h0 = fmaf(xf, uw1[i*128 + j0], h0);
        h1 = fmaf(xf, uw1[i*128 + j1], h1);
        h0 = fmaf(xh, uw1[(128 + i)*128 + j0], h0);
        h1 = fmaf(xh, uw1[(128 + i)*128 + j1], h1);
    }
    h0 = fmaxf(h0, 0.f); h1 = fmaxf(h1, 0.f);
    t1l[w][j0] = h0; t1l[w][j1] = h1;
    __syncthreads();
    float o0 = ub2[j0], o1 = ub2[j1];
    for (int i = 0; i < 128; ++i) {
        float x = t1l[w][i];
        o0 = fmaf(x, uw2[i*128 + j0], o0);
        o1 = fmaf(x, uw2[i*128 + j1], o1);
    }
    out[ob*CC + j0] = f0 + o0;
    out[ob*CC + j1] = f1 + o1;
}

extern "C" void kernel_launch(void* const* d_in, const int* in_sizes, int n_in,
                              void* d_out, int out_size, void* d_ws, size_t ws_size,
                              hipStream_t stream) {
    (void)in_sizes; (void)n_in; (void)out_size; (void)ws_size;
    const float* feature  = (const float*)d_in[0];
    const float* memory_x = (const float*)d_in[1];
    const int*   memory_y = (const int*)d_in[2];
    const float* seed_t   = (const float*)d_in[3];
    const float* mem_st   = (const float*)d_in[4];
    const float* key_w    = (const float*)d_in[5];
    const float* key_b    = (const float*)d_in[6];
    const float* msg_w    = (const float*)d_in[7];
    const float* msg_b    = (const float*)d_in[8];
    const float* upd_w1   = (const float*)d_in[9];
    const float* upd_b1   = (const float*)d_in[10];
    const float* upd_w2   = (const float*)d_in[11];
    const float* upd_b2   = (const float*)d_in[12];
    const float* y_emb    = (const float*)d_in[13];
    float* out = (float*)d_out;

    // ---- bump-allocated workspace (256B aligned) ----
    char* ws = (char*)d_ws;
    size_t off = 0;
    auto A = [&](size_t bytes) -> char* {
        char* p = ws + off;
        off += (bytes + 255) & ~(size_t)255;
        return p;
    };
    char* FK = A((size_t)(MM/64)*16*1024);                               // 16.78 MB
    char* FV = A((size_t)(MM/64)*16*1024);                               // 16.78 MB
    unsigned short* q2    = (unsigned short*)A((size_t)BQ*CC*2);         // 512 KB
    float* a      = (float*)A((size_t)BQ*CC*4);                          // 1 MB
    float* etab   = (float*)A(2*CC*4);
    float* lpart  = (float*)A((size_t)NQB*NSPLIT*QBS*4);                 // 512 KB
    float* wypart = (float*)A((size_t)NQB*NSPLIT*QBS*4);                 // 512 KB
    int*   dperm  = (int*)A((size_t)MM*4);                               // 256 KB
    float* mst_s  = (float*)A((size_t)MM*4);                             // 256 KB
    float* y_s    = (float*)A((size_t)MM*4);                             // 256 KB
    unsigned int* btot  = (unsigned int*)A(NBUCKET*4);
    unsigned int* gbase = (unsigned int*)A(NBUCKET*4);
    int*   qperm  = (int*)A(BQ*4);
    int*   qrank  = (int*)A(BQ*4);
    float* seed_s = (float*)A(BQ*4);
    int*   cqbuf  = (int*)A(BQ*4);
    unsigned int* histT = (unsigned int*)A((size_t)NBUCKET*256*4);       // 1 MB
    unsigned short* Upart = (unsigned short*)A((size_t)NQB*NSPLIT*QBS*CC*2); // 33.5 MB

    ka_kernel<<<512, 256, 0, stream>>>(seed_t, mem_st, qperm, qrank, seed_s, histT);
    sort_scanA_kernel<<<NBUCKET, 64, 0, stream>>>(histT, btot);
    sort_scanB_kernel<<<1, 1024, 0, stream>>>(btot, gbase);
    sort_scatter_kernel<<<MM/256, 256, 0, stream>>>(mem_st, histT, gbase, dperm, mst_s);
    sortfix_kernel<<<NBUCKET, 64, 0, stream>>>(mst_s, dperm, gbase, btot);
    kb_kernel<<<1153, 256, 0, stream>>>(memory_x, dperm, memory_y, FK, FV, y_s,
                                        feature, key_w, key_b, msg_w, msg_b, y_emb,
                                        qrank, q2, a, etab,
                                        seed_s, mst_s, gbase, btot, cqbuf);
    attn_kernel<<<NQB*NSPLIT, 256, 0, stream>>>(FK, FV, q2, cqbuf, y_s,
                                                Upart, lpart, wypart);
    final_kernel<<<BQ/4, 256, 0, stream>>>(feature, Upart, lpart, wypart, cqbuf,
                                           a, etab, msg_w, qperm,
                                           upd_w1, upd_b1, upd_w2, upd_b2, out);
}